// Round 4
// baseline (9809.086 us; speedup 1.0000x reference)
//
#include <hip/hip_runtime.h>
#include <hip/hip_bf16.h>

#define DEV __device__ __forceinline__

typedef __attribute__((ext_vector_type(4))) float f32x4;
typedef __attribute__((ext_vector_type(8))) short short8;
typedef __attribute__((ext_vector_type(8))) _Float16 f16x8;
typedef __attribute__((ext_vector_type(4))) int i32x4;
typedef __attribute__((ext_vector_type(4))) unsigned short u16x4;

typedef __attribute__((address_space(3))) void lds_void;
typedef const __attribute__((address_space(1))) void g_void;
#define GLOAD16(g, l) __builtin_amdgcn_global_load_lds((g_void*)(g), (lds_void*)(l), 16, 0, 0)

DEV unsigned short f2h(float f){ union{_Float16 h; unsigned short u;} c; c.h = (_Float16)f; return c.u; }
DEV float h2f(unsigned short u){ union{unsigned short u; _Float16 h;} c; c.u = u; return (float)c.h; }
DEV f16x8 as_f16x8(short8 s){ union{short8 s; f16x8 h;} c; c.s = s; return c.h; }
DEV float wsum(float v){
  #pragma unroll
  for(int o=32;o;o>>=1) v += __shfl_xor(v,o,64);
  return v;
}
DEV float wmax_(float v){
  #pragma unroll
  for(int o=32;o;o>>=1) v = fmaxf(v,__shfl_xor(v,o,64));
  return v;
}
// XOR swizzle for [rows][32 fp16] LDS tiles, row stride 64B, 16B units.
DEV int swz(int row, int unit){ return row*64 + ((unit ^ ((row>>1)&3))<<4); }

// ---------------- prep: W_gates fp32 -> fp16 bt-layout [n][C][h], bias [n][C] ---
// C (scan col order) for (g,k): C = (k>>5)*128 + ((k>>4)&1)*64 + g*16 + (k&15)
__global__ __launch_bounds__(256) void prep_wbt(const float* __restrict__ W,
    const float* __restrict__ BG, unsigned short* __restrict__ WBT, float* __restrict__ BIAS){
  int bid = blockIdx.x;                 // (g,n,k) row-major, 4096 blocks
  int g = bid>>10, n = (bid>>8)&3, k = bid&255;
  int C = ((k>>5)<<7) | (((k>>4)&1)<<6) | (g<<4) | (k&15);
  int h = threadIdx.x;
  WBT[((size_t)n*1024 + C)*256 + h] = f2h(W[(size_t)bid*256 + h]);
  if (h==0) BIAS[n*1024 + C] = BG[(g*4+n)*256 + k];
}

// ---------------- prep: R_gates fp32 -> int8 fragment layout + per-col scales ----
__global__ __launch_bounds__(256) void prep_rq(const float* __restrict__ R,
    signed char* __restrict__ RQ, float* __restrict__ SC){
  int bid = blockIdx.x;                 // (g,n,k)
  int g = bid>>10, n = (bid>>8)&3, k = bid&255;
  int h = threadIdx.x;
  float v = R[(size_t)bid*256 + h];
  float a = fabsf(v);
  float m = wmax_(a);
  __shared__ float red[4];
  int wv = threadIdx.x>>6, l = threadIdx.x&63;
  if (!l) red[wv] = m;
  __syncthreads();
  m = fmaxf(fmaxf(red[0],red[1]), fmaxf(red[2],red[3]));
  float s = fmaxf(m, 1e-20f) * (1.f/127.f);
  int q = (int)rintf(v/s);
  q = q > 127 ? 127 : (q < -127 ? -127 : q);
  int w  = k>>5, kblk = (k>>4)&1, f = (kblk<<2)|g, kf = h>>6;
  int ln = (k&15) | (((h>>4)&3)<<4);
  int j  = h&15;
  RQ[ (((size_t)(n*8+w)*32 + (f*4+kf))*64 + ln)*16 + j ] = (signed char)q;
  if (h==0){
    int C = (w<<7) | (kblk<<6) | (g<<4) | (k&15);
    SC[n*1024 + C] = s * (1.f/127.f);   // rec = SC * (acc_hi + acc_lo/127)
  }
}

// ---------------- prep: transpose fp32 [K][N] -> fp16 [N][K] ----------------------
__global__ __launch_bounds__(256) void transpose_cast(const float* __restrict__ IN,
    unsigned short* __restrict__ OUT, int K, int N){
  __shared__ float tile[32][33];
  int n0 = blockIdx.x*32, k0 = blockIdx.y*32;
  int c = threadIdx.x&31, r4 = threadIdx.x>>5;
  #pragma unroll
  for (int rr = r4; rr < 32; rr += 8) tile[rr][c] = IN[(size_t)(k0+rr)*N + n0 + c];
  __syncthreads();
  #pragma unroll
  for (int rr = r4; rr < 32; rr += 8) OUT[(size_t)(n0+rr)*K + k0 + c] = f2h(tile[c][rr]);
}

// ---------------- rmsnorm fp32 -> fp16 -------------------------------------------
__global__ __launch_bounds__(256) void rmsnorm_k(const float* __restrict__ X,
    const float* __restrict__ W, unsigned short* __restrict__ O){
  size_t row = blockIdx.x;
  const f32x4* xp = (const f32x4*)(X + row*1024);
  f32x4 v = xp[threadIdx.x];
  float s = v[0]*v[0]+v[1]*v[1]+v[2]*v[2]+v[3]*v[3];
  s = wsum(s);
  __shared__ float red[4];
  int wv = threadIdx.x>>6, l = threadIdx.x&63;
  if (!l) red[wv] = s;
  __syncthreads();
  float tot = red[0]+red[1]+red[2]+red[3];
  float rs = rsqrtf(tot*(1.f/1024.f) + 1e-6f);
  int c = threadIdx.x*4;
  u16x4 o;
  #pragma unroll
  for (int j=0;j<4;j++) o[j] = f2h(v[j]*rs*W[c+j]);
  *(u16x4*)(O + row*1024 + c) = o;
}

// ---------------- multihead LN + residual: x2 = x + LN(hs)*gn_w -------------------
__global__ __launch_bounds__(256) void ln_res_k(const unsigned short* __restrict__ HS,
    const float* __restrict__ X, const float* __restrict__ GNW, float* X2){
  int bid = blockIdx.x; int b = bid>>11, t = bid&2047;
  int wv = threadIdx.x>>6, l = threadIdx.x&63;   // wave = head
  const unsigned short* hp = HS + (((size_t)t*4 + wv)*8 + b)*256 + l*4;
  u16x4 hv = *(const u16x4*)hp;
  float v0=h2f(hv[0]), v1=h2f(hv[1]), v2=h2f(hv[2]), v3=h2f(hv[3]);
  float s  = wsum(v0+v1+v2+v3);
  float s2 = wsum(v0*v0+v1*v1+v2*v2+v3*v3);
  float mu = s*(1.f/256.f);
  float var = s2*(1.f/256.f) - mu*mu;
  float rs = rsqrtf(var + 1e-5f);
  size_t base = ((size_t)b*2048 + t)*1024 + wv*256 + l*4;
  const float* gw = GNW + wv*256 + l*4;
  float vv[4] = {v0,v1,v2,v3};
  #pragma unroll
  for (int j=0;j<4;j++) X2[base+j] = X[base+j] + (vv[j]-mu)*rs*gw[j];
}

// ---------------- GEMM bt-form: C[M,N] = A[M,K] * B[N,K]^T (fp16, fp32 acc) -------
// MODE 0: gx epilogue (scatter to [t][n][C][b] fp16 + bias)
// MODE 1: dual-B (Wg,Wu), S = silu(G)*U fp16
// MODE 2: out = X2 + acc (fp32; OF and X2 alias element-for-element, no restrict)
template<int MODE>
__global__ __launch_bounds__(256,2) void gemm_bt(
    const unsigned short* __restrict__ A, int lda,
    const unsigned short* __restrict__ B1, const unsigned short* __restrict__ B2, int ldb,
    int K, unsigned short* __restrict__ OB, float* OF,
    const float* X2, const float* __restrict__ BIAS){
  __shared__ __align__(16) char smA[128*64];
  __shared__ __align__(16) char smB[64*64];
  __shared__ __align__(16) char smB2[64*64];
  int tid = threadIdx.x, w = tid>>6, l = tid&63;
  int n0 = blockIdx.x*64, m0 = blockIdx.y*128, head = blockIdx.z;
  if constexpr (MODE==0){ A += (size_t)head*256; B1 += (size_t)head*1024*256; }
  f32x4 acc[4][2], acc2[4][2];
  f32x4 z = {0.f,0.f,0.f,0.f};
  #pragma unroll
  for (int mi=0;mi<4;mi++)
    #pragma unroll
    for (int ni=0;ni<2;ni++){ acc[mi][ni]=z; acc2[mi][ni]=z; }
  int wr = w>>1, wc = w&1;
  for (int kt = 0; kt < K; kt += 32){
    #pragma unroll
    for (int c2=0;c2<2;c2++){
      int p = w*128 + c2*64 + l;
      int rr = p>>2, u = (p&3) ^ ((rr>>1)&3);
      GLOAD16(A + (size_t)(m0+rr)*lda + kt + u*8, smA + (w*128 + c2*64)*16);
    }
    {
      int p = w*64 + l;
      int rr = p>>2, u = (p&3) ^ ((rr>>1)&3);
      GLOAD16(B1 + (size_t)(n0+rr)*ldb + kt + u*8, smB + (w*64)*16);
      if constexpr (MODE==1)
        GLOAD16(B2 + (size_t)(n0+rr)*ldb + kt + u*8, smB2 + (w*64)*16);
    }
    __syncthreads();
    short8 af[4], bf[2], bg[2];
    #pragma unroll
    for (int mi=0;mi<4;mi++) af[mi] = *(const short8*)(smA + swz(wr*64 + mi*16 + (l&15), l>>4));
    #pragma unroll
    for (int ni=0;ni<2;ni++){
      bf[ni] = *(const short8*)(smB + swz(wc*32 + ni*16 + (l&15), l>>4));
      if constexpr (MODE==1)
        bg[ni] = *(const short8*)(smB2 + swz(wc*32 + ni*16 + (l&15), l>>4));
    }
    #pragma unroll
    for (int mi=0;mi<4;mi++)
      #pragma unroll
      for (int ni=0;ni<2;ni++){
        acc[mi][ni] = __builtin_amdgcn_mfma_f32_16x16x32_f16(as_f16x8(af[mi]), as_f16x8(bf[ni]), acc[mi][ni], 0,0,0);
        if constexpr (MODE==1)
          acc2[mi][ni] = __builtin_amdgcn_mfma_f32_16x16x32_f16(as_f16x8(af[mi]), as_f16x8(bg[ni]), acc2[mi][ni], 0,0,0);
      }
    __syncthreads();
  }
  int rbase = m0 + wr*64, cbase = n0 + wc*32;
  #pragma unroll
  for (int mi=0;mi<4;mi++)
    #pragma unroll
    for (int ni=0;ni<2;ni++)
      #pragma unroll
      for (int j=0;j<4;j++){
        int gr = rbase + mi*16 + (l>>4)*4 + j;
        int gc = cbase + ni*16 + (l&15);
        float v = acc[mi][ni][j];
        if constexpr (MODE==0){
          int t = gr & 2047, b = gr >> 11;
          OB[ (((size_t)t*4 + head)*1024 + gc)*8 + b ] = f2h(v + BIAS[head*1024 + gc]);
        } else if constexpr (MODE==1){
          float u = acc2[mi][ni][j];
          float sg = v/(1.f + __expf(-v));
          OB[ (size_t)gr*2752 + gc ] = f2h(sg*u);
        } else {
          size_t idx = (size_t)gr*1024 + gc;
          OF[idx] = X2[idx] + v;
        }
      }
}

// ---------------- sLSTM scan: one WG per head, int8 weights in VGPRs --------------
// h feedback in split precision: h ~= (hi + lo/127)/127, hi/lo int8.
__global__ __launch_bounds__(512,2) void scan_k(
    const unsigned short* __restrict__ GX,   // [T][4][1024][8] fp16
    const signed char* __restrict__ RQ,      // frag-linear int8
    const float* __restrict__ SC,            // [4][1024]
    unsigned short* __restrict__ HS){        // [T][4][8][256] fp16
  int n = blockIdx.x;
  int tid = threadIdx.x, w = tid>>6, l = tid&63;
  __shared__ __align__(16) signed char hl_hi[16*272];
  __shared__ __align__(16) signed char hl_lo[16*272];
  for (int i = tid; i < 16*272; i += 512){ hl_hi[i] = 0; hl_lo[i] = 0; }

  i32x4 wf[8][4];
  {
    const i32x4* rp = (const i32x4*)RQ + (size_t)(n*8+w)*32*64;
    #pragma unroll
    for (int f=0; f<8; f++)
      #pragma unroll
      for (int kf=0; kf<4; kf++)
        wf[f][kf] = rp[(f*4+kf)*64 + l];
  }
  int klo = l & 15;
  float sc[8];
  #pragma unroll
  for (int f=0; f<8; f++) sc[f] = SC[n*1024 + w*128 + f*16 + klo];

  float cs[8], ns_[8], ms[8];
  #pragma unroll
  for (int i=0;i<8;i++){ cs[i]=0.f; ns_[i]=0.f; ms[i]=0.f; }

  u16x4 gxr[8];
  int r0 = ((l&31)>>4)*4;   // batch-row base for lanes < 32
  if (l < 32){
    #pragma unroll
    for (int f=0; f<8; f++)
      gxr[f] = *(const u16x4*)(GX + ((size_t)n*1024 + w*128 + f*16 + klo)*8 + r0);
  }
  __syncthreads();

  for (int t = 0; t < 2048; ++t){
    i32x4 afh[4], afl[4];
    #pragma unroll
    for (int kf=0;kf<4;kf++){
      afh[kf] = *(const i32x4*)(hl_hi + (l&15)*272 + kf*64 + (l>>4)*16);
      afl[kf] = *(const i32x4*)(hl_lo + (l&15)*272 + kf*64 + (l>>4)*16);
    }
    f32x4 recf[8];
    #pragma unroll
    for (int f=0; f<8; f++){
      i32x4 ah = {0,0,0,0}, al = {0,0,0,0};
      #pragma unroll
      for (int kf=0; kf<4; kf++){
        ah = __builtin_amdgcn_mfma_i32_16x16x64_i8(afh[kf], wf[f][kf], ah, 0,0,0);
        al = __builtin_amdgcn_mfma_i32_16x16x64_i8(afl[kf], wf[f][kf], al, 0,0,0);
      }
      #pragma unroll
      for (int j=0;j<4;j++)
        recf[f][j] = sc[f]*((float)ah[j] + (float)al[j]*(1.f/127.f));
    }
    __syncthreads();            // all hl reads complete before rewrites
    if (l < 32){
      #pragma unroll
      for (int kb=0; kb<2; kb++){
        #pragma unroll
        for (int j=0;j<4;j++){
          int si = kb*4 + j;
          float ip = h2f(gxr[kb*4+0][j]) + recf[kb*4+0][j];
          float fp = h2f(gxr[kb*4+1][j]) + recf[kb*4+1][j];
          float zp = h2f(gxr[kb*4+2][j]) + recf[kb*4+2][j];
          float op = h2f(gxr[kb*4+3][j]) + recf[kb*4+3][j];
          float m0v = ms[si];
          float mn = fmaxf(fp + m0v, ip);
          float ig = __expf(ip - mn);
          float fg = __expf(fp + m0v - mn);
          float e2 = __expf(2.f*zp);
          float tz = 1.f - 2.f/(e2 + 1.f);
          float og = 1.f/(1.f + __expf(-op));
          float c  = fg*cs[si] + ig*tz;
          float nn = fg*ns_[si] + ig;
          float h  = og*c/nn;
          cs[si]=c; ns_[si]=nn; ms[si]=mn;
          int row = r0 + j;
          int k = w*32 + kb*16 + klo;
          float h127 = fminf(fmaxf(h*127.f, -127.f), 127.f);
          float hiq = rintf(h127);
          float loq = rintf((h127 - hiq)*127.f);
          hl_hi[row*272 + k] = (signed char)(int)hiq;
          hl_lo[row*272 + k] = (signed char)(int)loq;
          HS[ (((size_t)t*4 + n)*8 + row)*256 + k ] = f2h(h);
        }
      }
      // prefetch gx for t+1 (hidden under next step's MFMAs)
      int tn = (t+1 < 2048) ? t+1 : 2047;
      #pragma unroll
      for (int f=0; f<8; f++)
        gxr[f] = *(const u16x4*)(GX + (((size_t)tn*4 + n)*1024 + w*128 + f*16 + klo)*8 + r0);
    }
    __syncthreads();            // hl writes visible for next step
  }
}

// ---------------- launch ----------------------------------------------------------
extern "C" void kernel_launch(void* const* d_in, const int* in_sizes, int n_in,
                              void* d_out, int out_size, void* d_ws, size_t ws_size,
                              hipStream_t stream){
  (void)in_sizes; (void)n_in; (void)out_size;
  const float* x    = (const float*)d_in[0];
  const float* ln1w = (const float*)d_in[1];
  const float* Wg_  = (const float*)d_in[2];
  const float* Rg_  = (const float*)d_in[3];
  const float* bg_  = (const float*)d_in[4];
  const float* gnw  = (const float*)d_in[5];
  const float* ln2w = (const float*)d_in[6];
  const float* Wgf  = (const float*)d_in[7];
  const float* Wuf  = (const float*)d_in[8];
  const float* Wdf  = (const float*)d_in[9];
  float* out = (float*)d_out;
  char* ws = (char*)d_ws;

  // lifetime-aliased workspace layout (total 187,858,944 B):
  //   [0 .. 20.1M)  persistent weights (wbt,bias,rq,sc2,wgt,wut,wdt)
  //   [20.1M..53.6M) xn (rms1 out) -> reused as hs (scan out)
  //   [53.6M..187.9M) gx (gate GEMM out) -> reused as y2 (rms2) + S (FFN mid)
  //   x2 lives in d_out (fp32, fully rewritten every launch)
  if (ws_size < 187858944ull) return;
  unsigned short* wbt = (unsigned short*)(ws + 0);
  float*          bias= (float*)        (ws + 2097152);
  signed char*    rq  = (signed char*)  (ws + 2113536);
  float*          sc2 = (float*)        (ws + 3162112);
  unsigned short* wgt = (unsigned short*)(ws + 3178496);
  unsigned short* wut = (unsigned short*)(ws + 8814592);
  unsigned short* wdt = (unsigned short*)(ws + 14450688);
  unsigned short* xn  = (unsigned short*)(ws + 20086784);
  unsigned short* hs  = (unsigned short*)(ws + 20086784);   // aliases xn
  unsigned short* gx  = (unsigned short*)(ws + 53641216);
  unsigned short* y2  = (unsigned short*)(ws + 53641216);   // aliases gx (dead)
  unsigned short* S   = (unsigned short*)(ws + 87195648);   // aliases gx tail
  float*          x2  = out;                                 // residual stream in d_out

  prep_wbt<<<4096,256,0,stream>>>(Wg_, bg_, wbt, bias);
  prep_rq <<<4096,256,0,stream>>>(Rg_, rq, sc2);
  transpose_cast<<<dim3(86,32),256,0,stream>>>(Wgf, wgt, 1024, 2752);
  transpose_cast<<<dim3(86,32),256,0,stream>>>(Wuf, wut, 1024, 2752);
  transpose_cast<<<dim3(32,86),256,0,stream>>>(Wdf, wdt, 2752, 1024);

  rmsnorm_k<<<16384,256,0,stream>>>(x, ln1w, xn);
  gemm_bt<0><<<dim3(16,128,4),256,0,stream>>>(xn, 1024, wbt, nullptr, 256, 256,
                                              gx, nullptr, nullptr, bias);
  scan_k<<<4,512,0,stream>>>(gx, rq, sc2, hs);
  ln_res_k<<<16384,256,0,stream>>>(hs, x, gnw, x2);
  rmsnorm_k<<<16384,256,0,stream>>>(x2, ln2w, y2);
  gemm_bt<1><<<dim3(43,128),256,0,stream>>>(y2, 1024, wgt, wut, 1024, 1024,
                                            S, nullptr, nullptr, nullptr);
  gemm_bt<2><<<dim3(16,128),256,0,stream>>>(S, 2752, wdt, nullptr, 2752, 2752,
                                            nullptr, out, x2, nullptr);
}

// Round 5
// 4433.564 us; speedup vs baseline: 2.2125x; 2.2125x over previous
//
#include <hip/hip_runtime.h>
#include <hip/hip_bf16.h>

#define DEV __device__ __forceinline__

typedef __attribute__((ext_vector_type(4))) float f32x4;
typedef __attribute__((ext_vector_type(8))) short short8;
typedef __attribute__((ext_vector_type(8))) _Float16 f16x8;
typedef __attribute__((ext_vector_type(4))) int i32x4;
typedef __attribute__((ext_vector_type(4))) unsigned short u16x4;

typedef __attribute__((address_space(3))) void lds_void;
typedef const __attribute__((address_space(1))) void g_void;
#define GLOAD16(g, l) __builtin_amdgcn_global_load_lds((g_void*)(g), (lds_void*)(l), 16, 0, 0)

DEV unsigned short f2h(float f){ union{_Float16 h; unsigned short u;} c; c.h = (_Float16)f; return c.u; }
DEV float h2f(unsigned short u){ union{unsigned short u; _Float16 h;} c; c.u = u; return (float)c.h; }
DEV f16x8 as_f16x8(short8 s){ union{short8 s; f16x8 h;} c; c.s = s; return c.h; }
DEV float wsum(float v){
  #pragma unroll
  for(int o=32;o;o>>=1) v += __shfl_xor(v,o,64);
  return v;
}
DEV float wmax_(float v){
  #pragma unroll
  for(int o=32;o;o>>=1) v = fmaxf(v,__shfl_xor(v,o,64));
  return v;
}
// XOR swizzle for [rows][32 fp16] LDS tiles, row stride 64B, 16B units.
DEV int swz(int row, int unit){ return row*64 + ((unit ^ ((row>>1)&3))<<4); }

// ---------------- prep: W_gates fp32 -> fp16 bt-layout [n][C][h], bias [n][C] ---
// C (scan col order) for (g,k): C = (k>>5)*128 + ((k>>4)&1)*64 + g*16 + (k&15)
__global__ __launch_bounds__(256) void prep_wbt(const float* __restrict__ W,
    const float* __restrict__ BG, unsigned short* __restrict__ WBT, float* __restrict__ BIAS){
  int bid = blockIdx.x;                 // (g,n,k) row-major, 4096 blocks
  int g = bid>>10, n = (bid>>8)&3, k = bid&255;
  int C = ((k>>5)<<7) | (((k>>4)&1)<<6) | (g<<4) | (k&15);
  int h = threadIdx.x;
  WBT[((size_t)n*1024 + C)*256 + h] = f2h(W[(size_t)bid*256 + h]);
  if (h==0) BIAS[n*1024 + C] = BG[(g*4+n)*256 + k];
}

// ---------------- prep: R_gates fp32 -> int8 fragment layout + per-col scales ----
__global__ __launch_bounds__(256) void prep_rq(const float* __restrict__ R,
    signed char* __restrict__ RQ, float* __restrict__ SC){
  int bid = blockIdx.x;                 // (g,n,k)
  int g = bid>>10, n = (bid>>8)&3, k = bid&255;
  int h = threadIdx.x;
  float v = R[(size_t)bid*256 + h];
  float a = fabsf(v);
  float m = wmax_(a);
  __shared__ float red[4];
  int wv = threadIdx.x>>6, l = threadIdx.x&63;
  if (!l) red[wv] = m;
  __syncthreads();
  m = fmaxf(fmaxf(red[0],red[1]), fmaxf(red[2],red[3]));
  float s = fmaxf(m, 1e-20f) * (1.f/127.f);
  int q = (int)rintf(v/s);
  q = q > 127 ? 127 : (q < -127 ? -127 : q);
  int w  = k>>5, kblk = (k>>4)&1, f = (kblk<<2)|g, kf = h>>6;
  int ln = (k&15) | (((h>>4)&3)<<4);
  int j  = h&15;
  RQ[ (((size_t)(n*8+w)*32 + (f*4+kf))*64 + ln)*16 + j ] = (signed char)q;
  if (h==0){
    int C = (w<<7) | (kblk<<6) | (g<<4) | (k&15);
    SC[n*1024 + C] = s * (1.f/127.f);   // rec = SC * (acc_hi + acc_lo/127)
  }
}

// ---------------- prep: transpose fp32 [K][N] -> fp16 [N][K] ----------------------
__global__ __launch_bounds__(256) void transpose_cast(const float* __restrict__ IN,
    unsigned short* __restrict__ OUT, int K, int N){
  __shared__ float tile[32][33];
  int n0 = blockIdx.x*32, k0 = blockIdx.y*32;
  int c = threadIdx.x&31, r4 = threadIdx.x>>5;
  #pragma unroll
  for (int rr = r4; rr < 32; rr += 8) tile[rr][c] = IN[(size_t)(k0+rr)*N + n0 + c];
  __syncthreads();
  #pragma unroll
  for (int rr = r4; rr < 32; rr += 8) OUT[(size_t)(n0+rr)*K + k0 + c] = f2h(tile[c][rr]);
}

// ---------------- rmsnorm fp32 -> fp16 -------------------------------------------
__global__ __launch_bounds__(256) void rmsnorm_k(const float* __restrict__ X,
    const float* __restrict__ W, unsigned short* __restrict__ O){
  size_t row = blockIdx.x;
  const f32x4* xp = (const f32x4*)(X + row*1024);
  f32x4 v = xp[threadIdx.x];
  float s = v[0]*v[0]+v[1]*v[1]+v[2]*v[2]+v[3]*v[3];
  s = wsum(s);
  __shared__ float red[4];
  int wv = threadIdx.x>>6, l = threadIdx.x&63;
  if (!l) red[wv] = s;
  __syncthreads();
  float tot = red[0]+red[1]+red[2]+red[3];
  float rs = rsqrtf(tot*(1.f/1024.f) + 1e-6f);
  int c = threadIdx.x*4;
  u16x4 o;
  #pragma unroll
  for (int j=0;j<4;j++) o[j] = f2h(v[j]*rs*W[c+j]);
  *(u16x4*)(O + row*1024 + c) = o;
}

// ---------------- multihead LN + residual: x2 = x + LN(hs)*gn_w -------------------
__global__ __launch_bounds__(256) void ln_res_k(const unsigned short* __restrict__ HS,
    const float* __restrict__ X, const float* __restrict__ GNW, float* X2){
  int bid = blockIdx.x; int b = bid>>11, t = bid&2047;
  int wv = threadIdx.x>>6, l = threadIdx.x&63;   // wave = head
  const unsigned short* hp = HS + (((size_t)t*4 + wv)*8 + b)*256 + l*4;
  u16x4 hv = *(const u16x4*)hp;
  float v0=h2f(hv[0]), v1=h2f(hv[1]), v2=h2f(hv[2]), v3=h2f(hv[3]);
  float s  = wsum(v0+v1+v2+v3);
  float s2 = wsum(v0*v0+v1*v1+v2*v2+v3*v3);
  float mu = s*(1.f/256.f);
  float var = s2*(1.f/256.f) - mu*mu;
  float rs = rsqrtf(var + 1e-5f);
  size_t base = ((size_t)b*2048 + t)*1024 + wv*256 + l*4;
  const float* gw = GNW + wv*256 + l*4;
  float vv[4] = {v0,v1,v2,v3};
  #pragma unroll
  for (int j=0;j<4;j++) X2[base+j] = X[base+j] + (vv[j]-mu)*rs*gw[j];
}

// ---------------- GEMM bt-form: C[M,N] = A[M,K] * B[N,K]^T (fp16, fp32 acc) -------
// MODE 0: gx epilogue (scatter to [t][n][C][b] fp16 + bias)
// MODE 1: dual-B (Wg,Wu), S = silu(G)*U fp16
// MODE 2: out = X2 + acc (fp32; OF and X2 alias element-for-element, no restrict)
template<int MODE>
__global__ __launch_bounds__(256,2) void gemm_bt(
    const unsigned short* __restrict__ A, int lda,
    const unsigned short* __restrict__ B1, const unsigned short* __restrict__ B2, int ldb,
    int K, unsigned short* __restrict__ OB, float* OF,
    const float* X2, const float* __restrict__ BIAS){
  __shared__ __align__(16) char smA[128*64];
  __shared__ __align__(16) char smB[64*64];
  __shared__ __align__(16) char smB2[64*64];
  int tid = threadIdx.x, w = tid>>6, l = tid&63;
  int n0 = blockIdx.x*64, m0 = blockIdx.y*128, head = blockIdx.z;
  if constexpr (MODE==0){ A += (size_t)head*256; B1 += (size_t)head*1024*256; }
  f32x4 acc[4][2], acc2[4][2];
  f32x4 z = {0.f,0.f,0.f,0.f};
  #pragma unroll
  for (int mi=0;mi<4;mi++)
    #pragma unroll
    for (int ni=0;ni<2;ni++){ acc[mi][ni]=z; acc2[mi][ni]=z; }
  int wr = w>>1, wc = w&1;
  for (int kt = 0; kt < K; kt += 32){
    #pragma unroll
    for (int c2=0;c2<2;c2++){
      int p = w*128 + c2*64 + l;
      int rr = p>>2, u = (p&3) ^ ((rr>>1)&3);
      GLOAD16(A + (size_t)(m0+rr)*lda + kt + u*8, smA + (w*128 + c2*64)*16);
    }
    {
      int p = w*64 + l;
      int rr = p>>2, u = (p&3) ^ ((rr>>1)&3);
      GLOAD16(B1 + (size_t)(n0+rr)*ldb + kt + u*8, smB + (w*64)*16);
      if constexpr (MODE==1)
        GLOAD16(B2 + (size_t)(n0+rr)*ldb + kt + u*8, smB2 + (w*64)*16);
    }
    __syncthreads();
    short8 af[4], bf[2], bg[2];
    #pragma unroll
    for (int mi=0;mi<4;mi++) af[mi] = *(const short8*)(smA + swz(wr*64 + mi*16 + (l&15), l>>4));
    #pragma unroll
    for (int ni=0;ni<2;ni++){
      bf[ni] = *(const short8*)(smB + swz(wc*32 + ni*16 + (l&15), l>>4));
      if constexpr (MODE==1)
        bg[ni] = *(const short8*)(smB2 + swz(wc*32 + ni*16 + (l&15), l>>4));
    }
    #pragma unroll
    for (int mi=0;mi<4;mi++)
      #pragma unroll
      for (int ni=0;ni<2;ni++){
        acc[mi][ni] = __builtin_amdgcn_mfma_f32_16x16x32_f16(as_f16x8(af[mi]), as_f16x8(bf[ni]), acc[mi][ni], 0,0,0);
        if constexpr (MODE==1)
          acc2[mi][ni] = __builtin_amdgcn_mfma_f32_16x16x32_f16(as_f16x8(af[mi]), as_f16x8(bg[ni]), acc2[mi][ni], 0,0,0);
      }
    __syncthreads();
  }
  int rbase = m0 + wr*64, cbase = n0 + wc*32;
  #pragma unroll
  for (int mi=0;mi<4;mi++)
    #pragma unroll
    for (int ni=0;ni<2;ni++)
      #pragma unroll
      for (int j=0;j<4;j++){
        int gr = rbase + mi*16 + (l>>4)*4 + j;
        int gc = cbase + ni*16 + (l&15);
        float v = acc[mi][ni][j];
        if constexpr (MODE==0){
          int t = gr & 2047, b = gr >> 11;
          OB[ (((size_t)t*4 + head)*1024 + gc)*8 + b ] = f2h(v + BIAS[head*1024 + gc]);
        } else if constexpr (MODE==1){
          float u = acc2[mi][ni][j];
          float sg = v/(1.f + __expf(-v));
          OB[ (size_t)gr*2752 + gc ] = f2h(sg*u);
        } else {
          size_t idx = (size_t)gr*1024 + gc;
          OF[idx] = X2[idx] + v;
        }
      }
}

// ---------------- sLSTM scan: one WG per head, int8 weights in VGPRs --------------
// h feedback split precision packed into ONE MFMA: A rows 0-7 = hi (int8 of h*127),
// rows 8-15 = lo (int8 of residual*127). C rows 0-7 = hi acc, rows 8-15 = lo acc;
// combined via one cross-half shuffle. Epilogue split: lanes<32 own kb=0 states,
// lanes>=32 own kb=1. Double-buffered hl -> single barrier per step.
__global__ __launch_bounds__(512,2) void scan_k(
    const unsigned short* __restrict__ GX,   // [T][4][1024][8] fp16
    const signed char* __restrict__ RQ,      // frag-linear int8
    const float* __restrict__ SC,            // [4][1024]
    unsigned short* __restrict__ HS){        // [T][4][8][256] fp16
  int n = blockIdx.x;
  int tid = threadIdx.x, w = tid>>6, l = tid&63;
  __shared__ __align__(16) signed char hl[2][16*272];
  for (int i = tid; i < 2*16*272; i += 512) ((signed char*)hl)[i] = 0;

  i32x4 wf[8][4];
  {
    const i32x4* rp = (const i32x4*)RQ + (size_t)(n*8+w)*32*64;
    #pragma unroll
    for (int f=0; f<8; f++)
      #pragma unroll
      for (int kf=0; kf<4; kf++)
        wf[f][kf] = rp[(f*4+kf)*64 + l];
  }
  int klo  = l & 15;
  int kb4  = (l>>5)*4;              // gate-block base: f = kb4+g
  int bb   = ((l>>4)&1)*4;          // batch base 0 or 4
  int kcol = w*32 + (l>>5)*16 + klo; // this lane's state column within the head
  bool hi_lane = (l < 32);

  float sc[4];
  #pragma unroll
  for (int g=0; g<4; g++) sc[g] = SC[n*1024 + w*128 + (kb4+g)*16 + klo];

  float cs[4], ns_[4], ms[4];
  #pragma unroll
  for (int i=0;i<4;i++){ cs[i]=0.f; ns_[i]=0.f; ms[i]=0.f; }

  u16x4 gxr[4];
  #pragma unroll
  for (int g=0; g<4; g++)
    gxr[g] = *(const u16x4*)(GX + ((size_t)n*1024 + w*128 + (kb4+g)*16 + klo)*8 + bb);
  __syncthreads();

  int p = 0;
  for (int t = 0; t < 2048; ++t){
    i32x4 af[4];
    #pragma unroll
    for (int kf=0;kf<4;kf++)
      af[kf] = *(const i32x4*)(&hl[p][(l&15)*272 + kf*64 + (l>>4)*16]);
    f32x4 accf[8];
    #pragma unroll
    for (int f=0; f<8; f++){
      i32x4 a = {0,0,0,0};
      #pragma unroll
      for (int kf=0; kf<4; kf++)
        a = __builtin_amdgcn_mfma_i32_16x16x64_i8(af[kf], wf[f][kf], a, 0,0,0);
      #pragma unroll
      for (int j=0;j<4;j++) accf[f][j] = (float)a[j];
    }
    // combine hi(rows 0-7)/lo(rows 8-15) across wave halves: one shuffle per (g,j).
    // lane<32 sends accf[4+g] (hi of kb=1), receives partner's accf[g] (lo of kb=0);
    // lane>=32 sends accf[g], receives hi of kb=1.
    f32x4 recf[4];
    #pragma unroll
    for (int g=0; g<4; g++)
      #pragma unroll
      for (int j=0;j<4;j++){
        float send = hi_lane ? accf[4+g][j] : accf[g][j];
        float got  = __shfl_xor(send, 32, 64);
        float hi = hi_lane ? accf[g][j] : got;
        float lo = hi_lane ? got : accf[4+g][j];
        recf[g][j] = sc[g]*(hi + lo*(1.f/127.f));
      }
    #pragma unroll
    for (int j=0;j<4;j++){
      float ip = h2f(gxr[0][j]) + recf[0][j];
      float fp = h2f(gxr[1][j]) + recf[1][j];
      float zp = h2f(gxr[2][j]) + recf[2][j];
      float op = h2f(gxr[3][j]) + recf[3][j];
      float m0v = ms[j];
      float mn = fmaxf(fp + m0v, ip);
      float ig = __expf(ip - mn);
      float fg = __expf(fp + m0v - mn);
      float e2 = __expf(2.f*zp);
      float tz = 1.f - 2.f/(e2 + 1.f);
      float og = 1.f/(1.f + __expf(-op));
      float c  = fg*cs[j] + ig*tz;
      float nn = fg*ns_[j] + ig;
      float h  = og*c/nn;
      cs[j]=c; ns_[j]=nn; ms[j]=mn;
      float h127 = fminf(fmaxf(h*127.f, -127.f), 127.f);
      float hiq = rintf(h127);
      float loq = rintf((h127 - hiq)*127.f);
      hl[p^1][(bb+j)*272 + kcol]     = (signed char)(int)hiq;
      hl[p^1][(bb+j+8)*272 + kcol]   = (signed char)(int)loq;
      HS[ (((size_t)t*4 + n)*8 + bb + j)*256 + kcol ] = f2h(h);
    }
    // prefetch gx for t+1 (hides HBM latency under next step's MFMA phase)
    int tn = (t+1 < 2048) ? t+1 : 2047;
    #pragma unroll
    for (int g=0; g<4; g++)
      gxr[g] = *(const u16x4*)(GX + (((size_t)tn*4 + n)*1024 + w*128 + (kb4+g)*16 + klo)*8 + bb);
    __syncthreads();            // hl[p^1] writes visible; next step reads it
    p ^= 1;
  }
}

// ---------------- launch ----------------------------------------------------------
extern "C" void kernel_launch(void* const* d_in, const int* in_sizes, int n_in,
                              void* d_out, int out_size, void* d_ws, size_t ws_size,
                              hipStream_t stream){
  (void)in_sizes; (void)n_in; (void)out_size;
  const float* x    = (const float*)d_in[0];
  const float* ln1w = (const float*)d_in[1];
  const float* Wg_  = (const float*)d_in[2];
  const float* Rg_  = (const float*)d_in[3];
  const float* bg_  = (const float*)d_in[4];
  const float* gnw  = (const float*)d_in[5];
  const float* ln2w = (const float*)d_in[6];
  const float* Wgf  = (const float*)d_in[7];
  const float* Wuf  = (const float*)d_in[8];
  const float* Wdf  = (const float*)d_in[9];
  float* out = (float*)d_out;
  char* ws = (char*)d_ws;

  // lifetime-aliased workspace layout (total 187,858,944 B):
  //   [0 .. 20.1M)  persistent weights (wbt,bias,rq,sc2,wgt,wut,wdt)
  //   [20.1M..53.6M) xn (rms1 out) -> reused as hs (scan out)
  //   [53.6M..187.9M) gx (gate GEMM out) -> reused as y2 (rms2) + S (FFN mid)
  //   x2 lives in d_out (fp32, fully rewritten every launch)
  if (ws_size < 187858944ull) return;
  unsigned short* wbt = (unsigned short*)(ws + 0);
  float*          bias= (float*)        (ws + 2097152);
  signed char*    rq  = (signed char*)  (ws + 2113536);
  float*          sc2 = (float*)        (ws + 3162112);
  unsigned short* wgt = (unsigned short*)(ws + 3178496);
  unsigned short* wut = (unsigned short*)(ws + 8814592);
  unsigned short* wdt = (unsigned short*)(ws + 14450688);
  unsigned short* xn  = (unsigned short*)(ws + 20086784);
  unsigned short* hs  = (unsigned short*)(ws + 20086784);   // aliases xn
  unsigned short* gx  = (unsigned short*)(ws + 53641216);
  unsigned short* y2  = (unsigned short*)(ws + 53641216);   // aliases gx (dead)
  unsigned short* S   = (unsigned short*)(ws + 87195648);   // aliases gx tail
  float*          x2  = out;                                 // residual stream in d_out

  prep_wbt<<<4096,256,0,stream>>>(Wg_, bg_, wbt, bias);
  prep_rq <<<4096,256,0,stream>>>(Rg_, rq, sc2);
  transpose_cast<<<dim3(86,32),256,0,stream>>>(Wgf, wgt, 1024, 2752);
  transpose_cast<<<dim3(86,32),256,0,stream>>>(Wuf, wut, 1024, 2752);
  transpose_cast<<<dim3(32,86),256,0,stream>>>(Wdf, wdt, 2752, 1024);

  rmsnorm_k<<<16384,256,0,stream>>>(x, ln1w, xn);
  gemm_bt<0><<<dim3(16,128,4),256,0,stream>>>(xn, 1024, wbt, nullptr, 256, 256,
                                              gx, nullptr, nullptr, bias);
  scan_k<<<4,512,0,stream>>>(gx, rq, sc2, hs);
  ln_res_k<<<16384,256,0,stream>>>(hs, x, gnw, x2);
  rmsnorm_k<<<16384,256,0,stream>>>(x2, ln2w, y2);
  gemm_bt<1><<<dim3(43,128),256,0,stream>>>(y2, 1024, wgt, wut, 1024, 1024,
                                            S, nullptr, nullptr, nullptr);
  gemm_bt<2><<<dim3(16,128),256,0,stream>>>(S, 2752, wdt, nullptr, 2752, 2752,
                                            nullptr, out, x2, nullptr);
}

// Round 6
// 4033.796 us; speedup vs baseline: 2.4317x; 1.0991x over previous
//
#include <hip/hip_runtime.h>
#include <hip/hip_bf16.h>

#define DEV __device__ __forceinline__

typedef __attribute__((ext_vector_type(4))) float f32x4;
typedef __attribute__((ext_vector_type(8))) short short8;
typedef __attribute__((ext_vector_type(8))) _Float16 f16x8;
typedef __attribute__((ext_vector_type(4))) int i32x4;
typedef __attribute__((ext_vector_type(4))) unsigned short u16x4;
typedef __attribute__((ext_vector_type(8))) unsigned short u16x8;

typedef __attribute__((address_space(3))) void lds_void;
typedef const __attribute__((address_space(1))) void g_void;
#define GLOAD16(g, l) __builtin_amdgcn_global_load_lds((g_void*)(g), (lds_void*)(l), 16, 0, 0)

DEV unsigned short f2h(float f){ union{_Float16 h; unsigned short u;} c; c.h = (_Float16)f; return c.u; }
DEV float h2f(unsigned short u){ union{unsigned short u; _Float16 h;} c; c.u = u; return (float)c.h; }
DEV f16x8 as_f16x8(short8 s){ union{short8 s; f16x8 h;} c; c.s = s; return c.h; }
DEV float fexp2(float x){
#if __has_builtin(__builtin_amdgcn_exp2f)
  return __builtin_amdgcn_exp2f(x);
#else
  return exp2f(x);
#endif
}
DEV float frcp(float x){
#if __has_builtin(__builtin_amdgcn_rcpf)
  return __builtin_amdgcn_rcpf(x);
#else
  return 1.f/x;
#endif
}
DEV float wsum(float v){
  #pragma unroll
  for(int o=32;o;o>>=1) v += __shfl_xor(v,o,64);
  return v;
}
DEV float wmax_(float v){
  #pragma unroll
  for(int o=32;o;o>>=1) v = fmaxf(v,__shfl_xor(v,o,64));
  return v;
}
// XOR swizzle for [rows][32 fp16] LDS tiles, row stride 64B, 16B units.
DEV int swz(int row, int unit){ return row*64 + ((unit ^ ((row>>1)&3))<<4); }

// ---------------- prep: W_gates fp32 -> fp16 bt-layout [n][g*256+k][h] -----------
__global__ __launch_bounds__(256) void prep_wbt(const float* __restrict__ W,
    const float* __restrict__ BG, unsigned short* __restrict__ WBT, float* __restrict__ BIAS){
  int bid = blockIdx.x;                 // (g,n,k) row-major, 4096 blocks
  int g = bid>>10, n = (bid>>8)&3, k = bid&255;
  int C = g*256 + k;                    // natural column code
  int h = threadIdx.x;
  WBT[((size_t)n*1024 + C)*256 + h] = f2h(W[(size_t)bid*256 + h]);
  if (h==0) BIAS[n*1024 + C] = BG[(g*4+n)*256 + k];
}

// ---------------- prep: R_gates fp32 -> int8 fragment layout + per-col scales ----
__global__ __launch_bounds__(256) void prep_rq(const float* __restrict__ R,
    signed char* __restrict__ RQ, float* __restrict__ SC){
  int bid = blockIdx.x;                 // (g,n,k)
  int g = bid>>10, n = (bid>>8)&3, k = bid&255;
  int h = threadIdx.x;
  float v = R[(size_t)bid*256 + h];
  float a = fabsf(v);
  float m = wmax_(a);
  __shared__ float red[4];
  int wv = threadIdx.x>>6, l = threadIdx.x&63;
  if (!l) red[wv] = m;
  __syncthreads();
  m = fmaxf(fmaxf(red[0],red[1]), fmaxf(red[2],red[3]));
  float s = fmaxf(m, 1e-20f) * (1.f/127.f);
  int q = (int)rintf(v/s);
  q = q > 127 ? 127 : (q < -127 ? -127 : q);
  int w  = k>>5, kblk = (k>>4)&1, f = (kblk<<2)|g, kf = h>>6;
  int ln = (k&15) | (((h>>4)&3)<<4);
  int j  = h&15;
  RQ[ (((size_t)(n*8+w)*32 + (f*4+kf))*64 + ln)*16 + j ] = (signed char)q;
  if (h==0) SC[n*1024 + g*256 + k] = s * (1.f/127.f);  // rec = SC*(acc_hi + acc_lo/127)
}

// ---------------- prep: transpose fp32 [K][N] -> fp16 [N][K] ----------------------
__global__ __launch_bounds__(256) void transpose_cast(const float* __restrict__ IN,
    unsigned short* __restrict__ OUT, int K, int N){
  __shared__ float tile[32][33];
  int n0 = blockIdx.x*32, k0 = blockIdx.y*32;
  int c = threadIdx.x&31, r4 = threadIdx.x>>5;
  #pragma unroll
  for (int rr = r4; rr < 32; rr += 8) tile[rr][c] = IN[(size_t)(k0+rr)*N + n0 + c];
  __syncthreads();
  #pragma unroll
  for (int rr = r4; rr < 32; rr += 8) OUT[(size_t)(n0+rr)*K + k0 + c] = f2h(tile[c][rr]);
}

// ---------------- rmsnorm fp32 -> fp16 -------------------------------------------
__global__ __launch_bounds__(256) void rmsnorm_k(const float* __restrict__ X,
    const float* __restrict__ W, unsigned short* __restrict__ O){
  size_t row = blockIdx.x;
  const f32x4* xp = (const f32x4*)(X + row*1024);
  f32x4 v = xp[threadIdx.x];
  float s = v[0]*v[0]+v[1]*v[1]+v[2]*v[2]+v[3]*v[3];
  s = wsum(s);
  __shared__ float red[4];
  int wv = threadIdx.x>>6, l = threadIdx.x&63;
  if (!l) red[wv] = s;
  __syncthreads();
  float tot = red[0]+red[1]+red[2]+red[3];
  float rs = rsqrtf(tot*(1.f/1024.f) + 1e-6f);
  int c = threadIdx.x*4;
  u16x4 o;
  #pragma unroll
  for (int j=0;j<4;j++) o[j] = f2h(v[j]*rs*W[c+j]);
  *(u16x4*)(O + row*1024 + c) = o;
}

// ---------------- multihead LN + residual: x2 = x + LN(hs)*gn_w -------------------
__global__ __launch_bounds__(256) void ln_res_k(const unsigned short* __restrict__ HS,
    const float* __restrict__ X, const float* __restrict__ GNW, float* X2){
  int bid = blockIdx.x; int b = bid>>11, t = bid&2047;
  int wv = threadIdx.x>>6, l = threadIdx.x&63;   // wave = head
  const unsigned short* hp = HS + (((size_t)t*4 + wv)*8 + b)*256 + l*4;
  u16x4 hv = *(const u16x4*)hp;
  float v0=h2f(hv[0]), v1=h2f(hv[1]), v2=h2f(hv[2]), v3=h2f(hv[3]);
  float s  = wsum(v0+v1+v2+v3);
  float s2 = wsum(v0*v0+v1*v1+v2*v2+v3*v3);
  float mu = s*(1.f/256.f);
  float var = s2*(1.f/256.f) - mu*mu;
  float rs = rsqrtf(var + 1e-5f);
  size_t base = ((size_t)b*2048 + t)*1024 + wv*256 + l*4;
  const float* gw = GNW + wv*256 + l*4;
  float vv[4] = {v0,v1,v2,v3};
  #pragma unroll
  for (int j=0;j<4;j++) X2[base+j] = X[base+j] + (vv[j]-mu)*rs*gw[j];
}

// ---------------- GEMM bt-form: C[M,N] = A[M,K] * B[N,K]^T (fp16, fp32 acc) -------
// MODE 0: gx epilogue -> [t][n][k][q][g][2b] fp16 + bias
// MODE 1: dual-B (Wg,Wu), S = silu(G)*U fp16
// MODE 2: out = X2 + acc (fp32; OF and X2 alias element-for-element, no restrict)
template<int MODE>
__global__ __launch_bounds__(256,2) void gemm_bt(
    const unsigned short* __restrict__ A, int lda,
    const unsigned short* __restrict__ B1, const unsigned short* __restrict__ B2, int ldb,
    int K, unsigned short* __restrict__ OB, float* OF,
    const float* X2, const float* __restrict__ BIAS){
  __shared__ __align__(16) char smA[128*64];
  __shared__ __align__(16) char smB[64*64];
  __shared__ __align__(16) char smB2[64*64];
  int tid = threadIdx.x, w = tid>>6, l = tid&63;
  int n0 = blockIdx.x*64, m0 = blockIdx.y*128, head = blockIdx.z;
  if constexpr (MODE==0){ A += (size_t)head*256; B1 += (size_t)head*1024*256; }
  f32x4 acc[4][2], acc2[4][2];
  f32x4 z = {0.f,0.f,0.f,0.f};
  #pragma unroll
  for (int mi=0;mi<4;mi++)
    #pragma unroll
    for (int ni=0;ni<2;ni++){ acc[mi][ni]=z; acc2[mi][ni]=z; }
  int wr = w>>1, wc = w&1;
  for (int kt = 0; kt < K; kt += 32){
    #pragma unroll
    for (int c2=0;c2<2;c2++){
      int p = w*128 + c2*64 + l;
      int rr = p>>2, u = (p&3) ^ ((rr>>1)&3);
      GLOAD16(A + (size_t)(m0+rr)*lda + kt + u*8, smA + (w*128 + c2*64)*16);
    }
    {
      int p = w*64 + l;
      int rr = p>>2, u = (p&3) ^ ((rr>>1)&3);
      GLOAD16(B1 + (size_t)(n0+rr)*ldb + kt + u*8, smB + (w*64)*16);
      if constexpr (MODE==1)
        GLOAD16(B2 + (size_t)(n0+rr)*ldb + kt + u*8, smB2 + (w*64)*16);
    }
    __syncthreads();
    short8 af[4], bf[2], bg[2];
    #pragma unroll
    for (int mi=0;mi<4;mi++) af[mi] = *(const short8*)(smA + swz(wr*64 + mi*16 + (l&15), l>>4));
    #pragma unroll
    for (int ni=0;ni<2;ni++){
      bf[ni] = *(const short8*)(smB + swz(wc*32 + ni*16 + (l&15), l>>4));
      if constexpr (MODE==1)
        bg[ni] = *(const short8*)(smB2 + swz(wc*32 + ni*16 + (l&15), l>>4));
    }
    #pragma unroll
    for (int mi=0;mi<4;mi++)
      #pragma unroll
      for (int ni=0;ni<2;ni++){
        acc[mi][ni] = __builtin_amdgcn_mfma_f32_16x16x32_f16(as_f16x8(af[mi]), as_f16x8(bf[ni]), acc[mi][ni], 0,0,0);
        if constexpr (MODE==1)
          acc2[mi][ni] = __builtin_amdgcn_mfma_f32_16x16x32_f16(as_f16x8(af[mi]), as_f16x8(bg[ni]), acc2[mi][ni], 0,0,0);
      }
    __syncthreads();
  }
  int rbase = m0 + wr*64, cbase = n0 + wc*32;
  #pragma unroll
  for (int mi=0;mi<4;mi++)
    #pragma unroll
    for (int ni=0;ni<2;ni++)
      #pragma unroll
      for (int j=0;j<4;j++){
        int gr = rbase + mi*16 + (l>>4)*4 + j;
        int gc = cbase + ni*16 + (l&15);
        float v = acc[mi][ni][j];
        if constexpr (MODE==0){
          int t = gr & 2047, b = gr >> 11;
          int g = gc >> 8, k = gc & 255;
          OB[ ((((size_t)t*4 + head)*256 + k)*4 + (b>>1))*8 + g*2 + (b&1) ]
            = f2h(v + BIAS[head*1024 + gc]);
        } else if constexpr (MODE==1){
          float u = acc2[mi][ni][j];
          float sg = v*frcp(1.f + fexp2(-v*1.44269504f));
          OB[ (size_t)gr*2752 + gc ] = f2h(sg*u);
        } else {
          size_t idx = (size_t)gr*1024 + gc;
          OF[idx] = X2[idx] + v;
        }
      }
}

// ---------------- sLSTM scan: one WG per head, int8 weights in VGPRs --------------
// A-row packing: row = 2*batch + (0=hi,1=lo). C quadrants then give each lane
// hi+lo for its own 4 states (b=2q+db, k = w*32 + kb*16 + l15) -> NO shuffles.
// Gate math in exp2/log2 domain with v_rcp/v_exp. Double-buffered hl, 1 barrier.
__global__ __launch_bounds__(512,2) void scan_k(
    const unsigned short* __restrict__ GX,   // [T][4][256 k][4 q][4 g][2 db] fp16
    const signed char* __restrict__ RQ,      // frag-linear int8
    const float* __restrict__ SC,            // [4][g*256+k]
    unsigned short* __restrict__ HS){        // [T][4][8][256] fp16
  int n = blockIdx.x;
  int tid = threadIdx.x, w = tid>>6, l = tid&63;
  __shared__ __align__(16) signed char hl[2][16*272];
  for (int i = tid; i < 2*16*272; i += 512) ((signed char*)hl)[i] = 0;

  i32x4 wf[8][4];
  {
    const i32x4* rp = (const i32x4*)RQ + (size_t)(n*8+w)*32*64;
    #pragma unroll
    for (int f=0; f<8; f++)
      #pragma unroll
      for (int kf=0; kf<4; kf++)
        wf[f][kf] = rp[(f*4+kf)*64 + l];
  }
  int l15 = l & 15, q = l >> 4;

  float sch[2][4], scl[2][4];
  #pragma unroll
  for (int kb=0; kb<2; kb++)
    #pragma unroll
    for (int g=0; g<4; g++){
      float s = SC[n*1024 + g*256 + w*32 + kb*16 + l15];
      sch[kb][g] = s; scl[kb][g] = s*(1.f/127.f);
    }

  float cs[2][2], ns_[2][2], ms[2][2];   // [kb][db]; m kept in log2 domain
  #pragma unroll
  for (int kb=0;kb<2;kb++)
    #pragma unroll
    for (int db=0;db<2;db++){ cs[kb][db]=0.f; ns_[kb][db]=0.f; ms[kb][db]=0.f; }

  const unsigned short* gp0 = GX + ((size_t)n*256 + w*32 + l15)*32 + q*8;
  const unsigned short* gp1 = gp0 + 16*32;
  u16x8 gxr[2];
  gxr[0] = *(const u16x8*)gp0;
  gxr[1] = *(const u16x8*)gp1;

  unsigned short* hsp = HS + ((size_t)n*8 + 2*q)*256 + w*32 + l15;
  int hlw = w*32 + l15;                   // hl col base for writes
  const float L2E = 1.44269504f;
  __syncthreads();

  int p = 0;
  for (int t = 0; t < 2048; ++t){
    i32x4 af[4];
    #pragma unroll
    for (int kf=0;kf<4;kf++)
      af[kf] = *(const i32x4*)(&hl[p][l15*272 + kf*64 + q*16]);
    i32x4 acc[8];
    #pragma unroll
    for (int f=0; f<8; f++){
      i32x4 a = {0,0,0,0};
      #pragma unroll
      for (int kf=0; kf<4; kf++)
        a = __builtin_amdgcn_mfma_i32_16x16x64_i8(af[kf], wf[f][kf], a, 0,0,0);
      acc[f] = a;
    }
    #pragma unroll
    for (int kb=0; kb<2; kb++)
      #pragma unroll
      for (int db=0; db<2; db++){
        float rec0 = sch[kb][0]*(float)acc[kb*4+0][2*db] + scl[kb][0]*(float)acc[kb*4+0][2*db+1];
        float rec1 = sch[kb][1]*(float)acc[kb*4+1][2*db] + scl[kb][1]*(float)acc[kb*4+1][2*db+1];
        float rec2 = sch[kb][2]*(float)acc[kb*4+2][2*db] + scl[kb][2]*(float)acc[kb*4+2][2*db+1];
        float rec3 = sch[kb][3]*(float)acc[kb*4+3][2*db] + scl[kb][3]*(float)acc[kb*4+3][2*db+1];
        float ip = h2f(gxr[kb][0+db]) + rec0;
        float fp = h2f(gxr[kb][2+db]) + rec1;
        float zp = h2f(gxr[kb][4+db]) + rec2;
        float op = h2f(gxr[kb][6+db]) + rec3;
        float ip2 = ip*L2E;
        float fp2 = fp*L2E + ms[kb][db];
        float mn = fmaxf(fp2, ip2);
        float ig = fexp2(ip2 - mn);
        float fg = fexp2(fp2 - mn);
        float e2 = fexp2(zp*(2.f*L2E));
        float tz = 1.f - 2.f*frcp(e2 + 1.f);
        float og = frcp(1.f + fexp2(-op*L2E));
        float c  = fg*cs[kb][db] + ig*tz;
        float nn = fg*ns_[kb][db] + ig;
        float h  = og*c*frcp(nn);
        cs[kb][db]=c; ns_[kb][db]=nn; ms[kb][db]=mn;
        float h127 = h*127.f;               // |h|<1 provably -> no clamp
        float hiq = rintf(h127);
        float loq = rintf((h127 - hiq)*127.f);
        hl[p^1][(4*q + 2*db + 0)*272 + hlw + kb*16] = (signed char)(int)hiq;
        hl[p^1][(4*q + 2*db + 1)*272 + hlw + kb*16] = (signed char)(int)loq;
        hsp[db*256 + kb*16] = f2h(h);
      }
    hsp += 8192;
    int adv = (t+1 < 2048) ? 32768 : 0;    // prefetch t+1 (clamped)
    gp0 += adv; gp1 += adv;
    gxr[0] = *(const u16x8*)gp0;
    gxr[1] = *(const u16x8*)gp1;
    __syncthreads();                        // hl[p^1] visible for next step
    p ^= 1;
  }
}

// ---------------- launch ----------------------------------------------------------
extern "C" void kernel_launch(void* const* d_in, const int* in_sizes, int n_in,
                              void* d_out, int out_size, void* d_ws, size_t ws_size,
                              hipStream_t stream){
  (void)in_sizes; (void)n_in; (void)out_size;
  const float* x    = (const float*)d_in[0];
  const float* ln1w = (const float*)d_in[1];
  const float* Wg_  = (const float*)d_in[2];
  const float* Rg_  = (const float*)d_in[3];
  const float* bg_  = (const float*)d_in[4];
  const float* gnw  = (const float*)d_in[5];
  const float* ln2w = (const float*)d_in[6];
  const float* Wgf  = (const float*)d_in[7];
  const float* Wuf  = (const float*)d_in[8];
  const float* Wdf  = (const float*)d_in[9];
  float* out = (float*)d_out;
  char* ws = (char*)d_ws;

  // lifetime-aliased workspace layout (total 187,858,944 B)
  if (ws_size < 187858944ull) return;
  unsigned short* wbt = (unsigned short*)(ws + 0);
  float*          bias= (float*)        (ws + 2097152);
  signed char*    rq  = (signed char*)  (ws + 2113536);
  float*          sc2 = (float*)        (ws + 3162112);
  unsigned short* wgt = (unsigned short*)(ws + 3178496);
  unsigned short* wut = (unsigned short*)(ws + 8814592);
  unsigned short* wdt = (unsigned short*)(ws + 14450688);
  unsigned short* xn  = (unsigned short*)(ws + 20086784);
  unsigned short* hs  = (unsigned short*)(ws + 20086784);   // aliases xn
  unsigned short* gx  = (unsigned short*)(ws + 53641216);
  unsigned short* y2  = (unsigned short*)(ws + 53641216);   // aliases gx (dead)
  unsigned short* S   = (unsigned short*)(ws + 87195648);   // aliases gx tail
  float*          x2  = out;                                 // residual stream in d_out

  prep_wbt<<<4096,256,0,stream>>>(Wg_, bg_, wbt, bias);
  prep_rq <<<4096,256,0,stream>>>(Rg_, rq, sc2);
  transpose_cast<<<dim3(86,32),256,0,stream>>>(Wgf, wgt, 1024, 2752);
  transpose_cast<<<dim3(86,32),256,0,stream>>>(Wuf, wut, 1024, 2752);
  transpose_cast<<<dim3(32,86),256,0,stream>>>(Wdf, wdt, 2752, 1024);

  rmsnorm_k<<<16384,256,0,stream>>>(x, ln1w, xn);
  gemm_bt<0><<<dim3(16,128,4),256,0,stream>>>(xn, 1024, wbt, nullptr, 256, 256,
                                              gx, nullptr, nullptr, bias);
  scan_k<<<4,512,0,stream>>>(gx, rq, sc2, hs);
  ln_res_k<<<16384,256,0,stream>>>(hs, x, gnw, x2);
  rmsnorm_k<<<16384,256,0,stream>>>(x2, ln2w, y2);
  gemm_bt<1><<<dim3(43,128),256,0,stream>>>(y2, 1024, wgt, wut, 1024, 1024,
                                            S, nullptr, nullptr, nullptr);
  gemm_bt<2><<<dim3(16,128),256,0,stream>>>(S, 2752, wdt, nullptr, 2752, 2752,
                                            nullptr, out, x2, nullptr);
}

// Round 7
// 4019.075 us; speedup vs baseline: 2.4406x; 1.0037x over previous
//
#include <hip/hip_runtime.h>
#include <hip/hip_bf16.h>

#define DEV __device__ __forceinline__

typedef __attribute__((ext_vector_type(4))) float f32x4;
typedef __attribute__((ext_vector_type(8))) short short8;
typedef __attribute__((ext_vector_type(8))) _Float16 f16x8;
typedef __attribute__((ext_vector_type(4))) int i32x4;
typedef __attribute__((ext_vector_type(4))) unsigned short u16x4;
typedef __attribute__((ext_vector_type(8))) unsigned short u16x8;

typedef __attribute__((address_space(3))) void lds_void;
typedef const __attribute__((address_space(1))) void g_void;
#define GLOAD16(g, l) __builtin_amdgcn_global_load_lds((g_void*)(g), (lds_void*)(l), 16, 0, 0)

DEV unsigned short f2h(float f){ union{_Float16 h; unsigned short u;} c; c.h = (_Float16)f; return c.u; }
DEV float h2f(unsigned short u){ union{unsigned short u; _Float16 h;} c; c.u = u; return (float)c.h; }
DEV f16x8 as_f16x8(short8 s){ union{short8 s; f16x8 h;} c; c.s = s; return c.h; }
DEV float fexp2(float x){
#if __has_builtin(__builtin_amdgcn_exp2f)
  return __builtin_amdgcn_exp2f(x);
#else
  return exp2f(x);
#endif
}
DEV float frcp(float x){
#if __has_builtin(__builtin_amdgcn_rcpf)
  return __builtin_amdgcn_rcpf(x);
#else
  return 1.f/x;
#endif
}
DEV float wsum(float v){
  #pragma unroll
  for(int o=32;o;o>>=1) v += __shfl_xor(v,o,64);
  return v;
}
DEV float wmax_(float v){
  #pragma unroll
  for(int o=32;o;o>>=1) v = fmaxf(v,__shfl_xor(v,o,64));
  return v;
}
// XOR swizzle for [rows][32 fp16] LDS tiles, row stride 64B, 16B units.
DEV int swz(int row, int unit){ return row*64 + ((unit ^ ((row>>1)&3))<<4); }

// ---------------- prep: W_gates fp32 -> fp16 bt-layout [n][g*256+k][h] -----------
__global__ __launch_bounds__(256) void prep_wbt(const float* __restrict__ W,
    const float* __restrict__ BG, unsigned short* __restrict__ WBT, float* __restrict__ BIAS){
  int bid = blockIdx.x;                 // (g,n,k) row-major, 4096 blocks
  int g = bid>>10, n = (bid>>8)&3, k = bid&255;
  int C = g*256 + k;                    // natural column code
  int h = threadIdx.x;
  WBT[((size_t)n*1024 + C)*256 + h] = f2h(W[(size_t)bid*256 + h]);
  if (h==0) BIAS[n*1024 + C] = BG[(g*4+n)*256 + k];
}

// ---------------- prep: R_gates fp32 -> int8 fragment layout + per-col scales ----
__global__ __launch_bounds__(256) void prep_rq(const float* __restrict__ R,
    signed char* __restrict__ RQ, float* __restrict__ SC){
  int bid = blockIdx.x;                 // (g,n,k)
  int g = bid>>10, n = (bid>>8)&3, k = bid&255;
  int h = threadIdx.x;
  float v = R[(size_t)bid*256 + h];
  float a = fabsf(v);
  float m = wmax_(a);
  __shared__ float red[4];
  int wv = threadIdx.x>>6, l = threadIdx.x&63;
  if (!l) red[wv] = m;
  __syncthreads();
  m = fmaxf(fmaxf(red[0],red[1]), fmaxf(red[2],red[3]));
  float s = fmaxf(m, 1e-20f) * (1.f/127.f);
  int q = (int)rintf(v/s);
  q = q > 127 ? 127 : (q < -127 ? -127 : q);
  int w  = k>>5, kblk = (k>>4)&1, f = (kblk<<2)|g, kf = h>>6;
  int ln = (k&15) | (((h>>4)&3)<<4);
  int j  = h&15;
  RQ[ (((size_t)(n*8+w)*32 + (f*4+kf))*64 + ln)*16 + j ] = (signed char)q;
  if (h==0) SC[n*1024 + g*256 + k] = s * (1.f/127.f);  // rec = SC*(acc_hi + acc_lo/127)
}

// ---------------- prep: transpose fp32 [K][N] -> fp16 [N][K] ----------------------
__global__ __launch_bounds__(256) void transpose_cast(const float* __restrict__ IN,
    unsigned short* __restrict__ OUT, int K, int N){
  __shared__ float tile[32][33];
  int n0 = blockIdx.x*32, k0 = blockIdx.y*32;
  int c = threadIdx.x&31, r4 = threadIdx.x>>5;
  #pragma unroll
  for (int rr = r4; rr < 32; rr += 8) tile[rr][c] = IN[(size_t)(k0+rr)*N + n0 + c];
  __syncthreads();
  #pragma unroll
  for (int rr = r4; rr < 32; rr += 8) OUT[(size_t)(n0+rr)*K + k0 + c] = f2h(tile[c][rr]);
}

// ---------------- rmsnorm fp32 -> fp16 -------------------------------------------
__global__ __launch_bounds__(256) void rmsnorm_k(const float* __restrict__ X,
    const float* __restrict__ W, unsigned short* __restrict__ O){
  size_t row = blockIdx.x;
  const f32x4* xp = (const f32x4*)(X + row*1024);
  f32x4 v = xp[threadIdx.x];
  float s = v[0]*v[0]+v[1]*v[1]+v[2]*v[2]+v[3]*v[3];
  s = wsum(s);
  __shared__ float red[4];
  int wv = threadIdx.x>>6, l = threadIdx.x&63;
  if (!l) red[wv] = s;
  __syncthreads();
  float tot = red[0]+red[1]+red[2]+red[3];
  float rs = rsqrtf(tot*(1.f/1024.f) + 1e-6f);
  int c = threadIdx.x*4;
  u16x4 o;
  #pragma unroll
  for (int j=0;j<4;j++) o[j] = f2h(v[j]*rs*W[c+j]);
  *(u16x4*)(O + row*1024 + c) = o;
}

// ---------------- multihead LN + residual: x2 = x + LN(hs)*gn_w -------------------
__global__ __launch_bounds__(256) void ln_res_k(const unsigned short* __restrict__ HS,
    const float* __restrict__ X, const float* __restrict__ GNW, float* X2){
  int bid = blockIdx.x; int b = bid>>11, t = bid&2047;
  int wv = threadIdx.x>>6, l = threadIdx.x&63;   // wave = head
  const unsigned short* hp = HS + (((size_t)t*4 + wv)*8 + b)*256 + l*4;
  u16x4 hv = *(const u16x4*)hp;
  float v0=h2f(hv[0]), v1=h2f(hv[1]), v2=h2f(hv[2]), v3=h2f(hv[3]);
  float s  = wsum(v0+v1+v2+v3);
  float s2 = wsum(v0*v0+v1*v1+v2*v2+v3*v3);
  float mu = s*(1.f/256.f);
  float var = s2*(1.f/256.f) - mu*mu;
  float rs = rsqrtf(var + 1e-5f);
  size_t base = ((size_t)b*2048 + t)*1024 + wv*256 + l*4;
  const float* gw = GNW + wv*256 + l*4;
  float vv[4] = {v0,v1,v2,v3};
  #pragma unroll
  for (int j=0;j<4;j++) X2[base+j] = X[base+j] + (vv[j]-mu)*rs*gw[j];
}

// ---------------- GEMM bt-form: C[M,N] = A[M,K] * B[N,K]^T (fp16, fp32 acc) -------
// MODE 0: gx epilogue -> [t][n][k][q][g][2b] fp16 + bias
// MODE 1: dual-B (Wg,Wu), S = silu(G)*U fp16
// MODE 2: out = X2 + acc (fp32; OF and X2 alias element-for-element, no restrict)
template<int MODE>
__global__ __launch_bounds__(256,2) void gemm_bt(
    const unsigned short* __restrict__ A, int lda,
    const unsigned short* __restrict__ B1, const unsigned short* __restrict__ B2, int ldb,
    int K, unsigned short* __restrict__ OB, float* OF,
    const float* X2, const float* __restrict__ BIAS){
  __shared__ __align__(16) char smA[128*64];
  __shared__ __align__(16) char smB[64*64];
  __shared__ __align__(16) char smB2[64*64];
  int tid = threadIdx.x, w = tid>>6, l = tid&63;
  int n0 = blockIdx.x*64, m0 = blockIdx.y*128, head = blockIdx.z;
  if constexpr (MODE==0){ A += (size_t)head*256; B1 += (size_t)head*1024*256; }
  f32x4 acc[4][2], acc2[4][2];
  f32x4 z = {0.f,0.f,0.f,0.f};
  #pragma unroll
  for (int mi=0;mi<4;mi++)
    #pragma unroll
    for (int ni=0;ni<2;ni++){ acc[mi][ni]=z; acc2[mi][ni]=z; }
  int wr = w>>1, wc = w&1;
  for (int kt = 0; kt < K; kt += 32){
    #pragma unroll
    for (int c2=0;c2<2;c2++){
      int p = w*128 + c2*64 + l;
      int rr = p>>2, u = (p&3) ^ ((rr>>1)&3);
      GLOAD16(A + (size_t)(m0+rr)*lda + kt + u*8, smA + (w*128 + c2*64)*16);
    }
    {
      int p = w*64 + l;
      int rr = p>>2, u = (p&3) ^ ((rr>>1)&3);
      GLOAD16(B1 + (size_t)(n0+rr)*ldb + kt + u*8, smB + (w*64)*16);
      if constexpr (MODE==1)
        GLOAD16(B2 + (size_t)(n0+rr)*ldb + kt + u*8, smB2 + (w*64)*16);
    }
    __syncthreads();
    short8 af[4], bf[2], bg[2];
    #pragma unroll
    for (int mi=0;mi<4;mi++) af[mi] = *(const short8*)(smA + swz(wr*64 + mi*16 + (l&15), l>>4));
    #pragma unroll
    for (int ni=0;ni<2;ni++){
      bf[ni] = *(const short8*)(smB + swz(wc*32 + ni*16 + (l&15), l>>4));
      if constexpr (MODE==1)
        bg[ni] = *(const short8*)(smB2 + swz(wc*32 + ni*16 + (l&15), l>>4));
    }
    #pragma unroll
    for (int mi=0;mi<4;mi++)
      #pragma unroll
      for (int ni=0;ni<2;ni++){
        acc[mi][ni] = __builtin_amdgcn_mfma_f32_16x16x32_f16(as_f16x8(af[mi]), as_f16x8(bf[ni]), acc[mi][ni], 0,0,0);
        if constexpr (MODE==1)
          acc2[mi][ni] = __builtin_amdgcn_mfma_f32_16x16x32_f16(as_f16x8(af[mi]), as_f16x8(bg[ni]), acc2[mi][ni], 0,0,0);
      }
    __syncthreads();
  }
  int rbase = m0 + wr*64, cbase = n0 + wc*32;
  #pragma unroll
  for (int mi=0;mi<4;mi++)
    #pragma unroll
    for (int ni=0;ni<2;ni++)
      #pragma unroll
      for (int j=0;j<4;j++){
        int gr = rbase + mi*16 + (l>>4)*4 + j;
        int gc = cbase + ni*16 + (l&15);
        float v = acc[mi][ni][j];
        if constexpr (MODE==0){
          int t = gr & 2047, b = gr >> 11;
          int g = gc >> 8, k = gc & 255;
          OB[ ((((size_t)t*4 + head)*256 + k)*4 + (b>>1))*8 + g*2 + (b&1) ]
            = f2h(v + BIAS[head*1024 + gc]);
        } else if constexpr (MODE==1){
          float u = acc2[mi][ni][j];
          float sg = v*frcp(1.f + fexp2(-v*1.44269504f));
          OB[ (size_t)gr*2752 + gc ] = f2h(sg*u);
        } else {
          size_t idx = (size_t)gr*1024 + gc;
          OF[idx] = X2[idx] + v;
        }
      }
}

// ---------------- sLSTM scan: 16 waves/WG, 16 cols/wave, 2 states/lane -----------
// A-row packing: row = 2*batch + (0=hi,1=lo). C quadrant q rows 4q..4q+3 give each
// lane hi+lo for batches 2q,2q+1 at its column -> no shuffles, all lanes busy.
// Gate math in exp2 domain with v_rcp/v_exp. Double-buffered hl, 1 barrier/step.
__global__ __launch_bounds__(1024) void scan_k(
    const unsigned short* __restrict__ GX,   // [T][4][256 k][4 q][4 g][2 db] fp16
    const signed char* __restrict__ RQ,      // frag-linear int8
    const float* __restrict__ SC,            // [4][g*256+k]
    unsigned short* __restrict__ HS){        // [T][4][8][256] fp16
  int n = blockIdx.x;
  int tid = threadIdx.x, w = tid>>6, l = tid&63;
  __shared__ __align__(16) signed char hl[2][16*272];
  for (int i = tid; i < 2*16*272; i += 1024) ((signed char*)hl)[i] = 0;

  int l15 = l & 15, q = l >> 4;

  // B-frags: wave w covers 16 cols (coltile w) x 4 gates x 4 K-frags.
  // RQ layout from prep_rq: (((n*8 + w32)*32 + (f*4+kf))*64 + ln)*16 + j,
  // w32 = w>>1 (32-col group), f = ((w&1)<<2)|g.
  i32x4 wf[4][4];
  {
    const i32x4* rp = (const i32x4*)RQ + (size_t)(n*8 + (w>>1))*32*64;
    #pragma unroll
    for (int g=0; g<4; g++){
      int f = ((w&1)<<2) | g;
      #pragma unroll
      for (int kf=0; kf<4; kf++)
        wf[g][kf] = rp[(f*4+kf)*64 + l];
    }
  }

  float sch[4], scl[4];
  #pragma unroll
  for (int g=0; g<4; g++){
    float s = SC[n*1024 + g*256 + w*16 + l15];
    sch[g] = s; scl[g] = s*(1.f/127.f);
  }

  float cs[2], ns_[2], ms[2];   // per db; m kept in log2 domain
  #pragma unroll
  for (int db=0;db<2;db++){ cs[db]=0.f; ns_[db]=0.f; ms[db]=0.f; }

  const unsigned short* gp = GX + ((size_t)n*256 + w*16 + l15)*32 + q*8;
  u16x8 gxr = *(const u16x8*)gp;

  unsigned short* hsp = HS + ((size_t)n*8 + 2*q)*256 + w*16 + l15;
  int hlw = w*16 + l15;                   // hl col base
  int hrow = 4*q;                          // hl row base (batches 2q,2q+1)
  const float L2E = 1.44269504f;
  __syncthreads();

  int p = 0;
  for (int t = 0; t < 2048; ++t){
    i32x4 af[4];
    #pragma unroll
    for (int kf=0;kf<4;kf++)
      af[kf] = *(const i32x4*)(&hl[p][l15*272 + kf*64 + q*16]);
    i32x4 acc[4];
    #pragma unroll
    for (int g=0; g<4; g++){
      i32x4 a = {0,0,0,0};
      #pragma unroll
      for (int kf=0; kf<4; kf++)
        a = __builtin_amdgcn_mfma_i32_16x16x64_i8(af[kf], wf[g][kf], a, 0,0,0);
      acc[g] = a;
    }
    #pragma unroll
    for (int db=0; db<2; db++){
      float rec0 = sch[0]*(float)acc[0][2*db] + scl[0]*(float)acc[0][2*db+1];
      float rec1 = sch[1]*(float)acc[1][2*db] + scl[1]*(float)acc[1][2*db+1];
      float rec2 = sch[2]*(float)acc[2][2*db] + scl[2]*(float)acc[2][2*db+1];
      float rec3 = sch[3]*(float)acc[3][2*db] + scl[3]*(float)acc[3][2*db+1];
      float ip = h2f(gxr[0+db]) + rec0;
      float fp = h2f(gxr[2+db]) + rec1;
      float zp = h2f(gxr[4+db]) + rec2;
      float op = h2f(gxr[6+db]) + rec3;
      float ip2 = ip*L2E;
      float fp2 = fp*L2E + ms[db];
      float mn = fmaxf(fp2, ip2);
      float ig = fexp2(ip2 - mn);
      float fg = fexp2(fp2 - mn);
      float e2 = fexp2(zp*(2.f*L2E));
      float tz = 1.f - 2.f*frcp(e2 + 1.f);
      float og = frcp(1.f + fexp2(-op*L2E));
      float c  = fg*cs[db] + ig*tz;
      float nn = fg*ns_[db] + ig;
      float h  = og*c*frcp(nn);
      cs[db]=c; ns_[db]=nn; ms[db]=mn;
      float h127 = h*127.f;               // |h|<1 provably -> no clamp
      float hiq = rintf(h127);
      float loq = rintf((h127 - hiq)*127.f);
      hl[p^1][(hrow + 2*db + 0)*272 + hlw] = (signed char)(int)hiq;
      hl[p^1][(hrow + 2*db + 1)*272 + hlw] = (signed char)(int)loq;
      hsp[db*256] = f2h(h);
    }
    hsp += 8192;
    int adv = (t+1 < 2048) ? 32768 : 0;    // prefetch t+1 (clamped)
    gp += adv;
    gxr = *(const u16x8*)gp;
    __syncthreads();                        // hl[p^1] visible for next step
    p ^= 1;
  }
}

// ---------------- launch ----------------------------------------------------------
extern "C" void kernel_launch(void* const* d_in, const int* in_sizes, int n_in,
                              void* d_out, int out_size, void* d_ws, size_t ws_size,
                              hipStream_t stream){
  (void)in_sizes; (void)n_in; (void)out_size;
  const float* x    = (const float*)d_in[0];
  const float* ln1w = (const float*)d_in[1];
  const float* Wg_  = (const float*)d_in[2];
  const float* Rg_  = (const float*)d_in[3];
  const float* bg_  = (const float*)d_in[4];
  const float* gnw  = (const float*)d_in[5];
  const float* ln2w = (const float*)d_in[6];
  const float* Wgf  = (const float*)d_in[7];
  const float* Wuf  = (const float*)d_in[8];
  const float* Wdf  = (const float*)d_in[9];
  float* out = (float*)d_out;
  char* ws = (char*)d_ws;

  // lifetime-aliased workspace layout (total 187,858,944 B)
  if (ws_size < 187858944ull) return;
  unsigned short* wbt = (unsigned short*)(ws + 0);
  float*          bias= (float*)        (ws + 2097152);
  signed char*    rq  = (signed char*)  (ws + 2113536);
  float*          sc2 = (float*)        (ws + 3162112);
  unsigned short* wgt = (unsigned short*)(ws + 3178496);
  unsigned short* wut = (unsigned short*)(ws + 8814592);
  unsigned short* wdt = (unsigned short*)(ws + 14450688);
  unsigned short* xn  = (unsigned short*)(ws + 20086784);
  unsigned short* hs  = (unsigned short*)(ws + 20086784);   // aliases xn
  unsigned short* gx  = (unsigned short*)(ws + 53641216);
  unsigned short* y2  = (unsigned short*)(ws + 53641216);   // aliases gx (dead)
  unsigned short* S   = (unsigned short*)(ws + 87195648);   // aliases gx tail
  float*          x2  = out;                                 // residual stream in d_out

  prep_wbt<<<4096,256,0,stream>>>(Wg_, bg_, wbt, bias);
  prep_rq <<<4096,256,0,stream>>>(Rg_, rq, sc2);
  transpose_cast<<<dim3(86,32),256,0,stream>>>(Wgf, wgt, 1024, 2752);
  transpose_cast<<<dim3(86,32),256,0,stream>>>(Wuf, wut, 1024, 2752);
  transpose_cast<<<dim3(32,86),256,0,stream>>>(Wdf, wdt, 2752, 1024);

  rmsnorm_k<<<16384,256,0,stream>>>(x, ln1w, xn);
  gemm_bt<0><<<dim3(16,128,4),256,0,stream>>>(xn, 1024, wbt, nullptr, 256, 256,
                                              gx, nullptr, nullptr, bias);
  scan_k<<<4,1024,0,stream>>>(gx, rq, sc2, hs);
  ln_res_k<<<16384,256,0,stream>>>(hs, x, gnw, x2);
  rmsnorm_k<<<16384,256,0,stream>>>(x2, ln2w, y2);
  gemm_bt<1><<<dim3(43,128),256,0,stream>>>(y2, 1024, wgt, wut, 1024, 1024,
                                            S, nullptr, nullptr, nullptr);
  gemm_bt<2><<<dim3(16,128),256,0,stream>>>(S, 2752, wdt, nullptr, 2752, 2752,
                                            nullptr, out, x2, nullptr);
}

// Round 8
// 3835.030 us; speedup vs baseline: 2.5578x; 1.0480x over previous
//
#include <hip/hip_runtime.h>
#include <hip/hip_bf16.h>

#define DEV __device__ __forceinline__

typedef __attribute__((ext_vector_type(4))) float f32x4;
typedef __attribute__((ext_vector_type(8))) short short8;
typedef __attribute__((ext_vector_type(8))) _Float16 f16x8;
typedef __attribute__((ext_vector_type(4))) int i32x4;
typedef __attribute__((ext_vector_type(4))) unsigned short u16x4;
typedef __attribute__((ext_vector_type(8))) unsigned short u16x8;

typedef __attribute__((address_space(3))) void lds_void;
typedef const __attribute__((address_space(1))) void g_void;
#define GLOAD16(g, l) __builtin_amdgcn_global_load_lds((g_void*)(g), (lds_void*)(l), 16, 0, 0)

DEV unsigned short f2h(float f){ union{_Float16 h; unsigned short u;} c; c.h = (_Float16)f; return c.u; }
DEV float h2f(unsigned short u){ union{unsigned short u; _Float16 h;} c; c.u = u; return (float)c.h; }
DEV f16x8 as_f16x8(short8 s){ union{short8 s; f16x8 h;} c; c.s = s; return c.h; }
DEV float fexp2(float x){
#if __has_builtin(__builtin_amdgcn_exp2f)
  return __builtin_amdgcn_exp2f(x);
#else
  return exp2f(x);
#endif
}
DEV float frcp(float x){
#if __has_builtin(__builtin_amdgcn_rcpf)
  return __builtin_amdgcn_rcpf(x);
#else
  return 1.f/x;
#endif
}
DEV float wsum(float v){
  #pragma unroll
  for(int o=32;o;o>>=1) v += __shfl_xor(v,o,64);
  return v;
}
DEV float wmax_(float v){
  #pragma unroll
  for(int o=32;o;o>>=1) v = fmaxf(v,__shfl_xor(v,o,64));
  return v;
}
// XOR swizzle for [rows][32 fp16] LDS tiles, row stride 64B, 16B units.
DEV int swz(int row, int unit){ return row*64 + ((unit ^ ((row>>1)&3))<<4); }

// ---------------- prep: W_gates fp32 -> fp16 bt-layout [n][g*256+k][h] -----------
__global__ __launch_bounds__(256) void prep_wbt(const float* __restrict__ W,
    const float* __restrict__ BG, unsigned short* __restrict__ WBT, float* __restrict__ BIAS){
  int bid = blockIdx.x;                 // (g,n,k) row-major, 4096 blocks
  int g = bid>>10, n = (bid>>8)&3, k = bid&255;
  int C = g*256 + k;                    // natural column code
  int h = threadIdx.x;
  WBT[((size_t)n*1024 + C)*256 + h] = f2h(W[(size_t)bid*256 + h]);
  if (h==0) BIAS[n*1024 + C] = BG[(g*4+n)*256 + k];
}

// ---------------- prep: R_gates fp32 -> int8 fragment layout + per-col scales ----
__global__ __launch_bounds__(256) void prep_rq(const float* __restrict__ R,
    signed char* __restrict__ RQ, float* __restrict__ SC){
  int bid = blockIdx.x;                 // (g,n,k)
  int g = bid>>10, n = (bid>>8)&3, k = bid&255;
  int h = threadIdx.x;
  float v = R[(size_t)bid*256 + h];
  float a = fabsf(v);
  float m = wmax_(a);
  __shared__ float red[4];
  int wv = threadIdx.x>>6, l = threadIdx.x&63;
  if (!l) red[wv] = m;
  __syncthreads();
  m = fmaxf(fmaxf(red[0],red[1]), fmaxf(red[2],red[3]));
  float s = fmaxf(m, 1e-20f) * (1.f/127.f);
  int q = (int)rintf(v/s);
  q = q > 127 ? 127 : (q < -127 ? -127 : q);
  int w  = k>>5, kblk = (k>>4)&1, f = (kblk<<2)|g, kf = h>>6;
  int ln = (k&15) | (((h>>4)&3)<<4);
  int j  = h&15;
  RQ[ (((size_t)(n*8+w)*32 + (f*4+kf))*64 + ln)*16 + j ] = (signed char)q;
  if (h==0) SC[n*1024 + g*256 + k] = s * (1.f/127.f);  // rec = SC*(acc_hi + acc_lo/127)
}

// ---------------- prep: transpose fp32 [K][N] -> fp16 [N][K] ----------------------
__global__ __launch_bounds__(256) void transpose_cast(const float* __restrict__ IN,
    unsigned short* __restrict__ OUT, int K, int N){
  __shared__ float tile[32][33];
  int n0 = blockIdx.x*32, k0 = blockIdx.y*32;
  int c = threadIdx.x&31, r4 = threadIdx.x>>5;
  #pragma unroll
  for (int rr = r4; rr < 32; rr += 8) tile[rr][c] = IN[(size_t)(k0+rr)*N + n0 + c];
  __syncthreads();
  #pragma unroll
  for (int rr = r4; rr < 32; rr += 8) OUT[(size_t)(n0+rr)*K + k0 + c] = f2h(tile[c][rr]);
}

// ---------------- rmsnorm fp32 -> fp16 -------------------------------------------
__global__ __launch_bounds__(256) void rmsnorm_k(const float* __restrict__ X,
    const float* __restrict__ W, unsigned short* __restrict__ O){
  size_t row = blockIdx.x;
  const f32x4* xp = (const f32x4*)(X + row*1024);
  f32x4 v = xp[threadIdx.x];
  float s = v[0]*v[0]+v[1]*v[1]+v[2]*v[2]+v[3]*v[3];
  s = wsum(s);
  __shared__ float red[4];
  int wv = threadIdx.x>>6, l = threadIdx.x&63;
  if (!l) red[wv] = s;
  __syncthreads();
  float tot = red[0]+red[1]+red[2]+red[3];
  float rs = rsqrtf(tot*(1.f/1024.f) + 1e-6f);
  int c = threadIdx.x*4;
  u16x4 o;
  #pragma unroll
  for (int j=0;j<4;j++) o[j] = f2h(v[j]*rs*W[c+j]);
  *(u16x4*)(O + row*1024 + c) = o;
}

// ---------------- multihead LN + residual: x2 = x + LN(hs)*gn_w -------------------
__global__ __launch_bounds__(256) void ln_res_k(const unsigned short* __restrict__ HS,
    const float* __restrict__ X, const float* __restrict__ GNW, float* X2){
  int bid = blockIdx.x; int b = bid>>11, t = bid&2047;
  int wv = threadIdx.x>>6, l = threadIdx.x&63;   // wave = head
  const unsigned short* hp = HS + (((size_t)t*4 + wv)*8 + b)*256 + l*4;
  u16x4 hv = *(const u16x4*)hp;
  float v0=h2f(hv[0]), v1=h2f(hv[1]), v2=h2f(hv[2]), v3=h2f(hv[3]);
  float s  = wsum(v0+v1+v2+v3);
  float s2 = wsum(v0*v0+v1*v1+v2*v2+v3*v3);
  float mu = s*(1.f/256.f);
  float var = s2*(1.f/256.f) - mu*mu;
  float rs = rsqrtf(var + 1e-5f);
  size_t base = ((size_t)b*2048 + t)*1024 + wv*256 + l*4;
  const float* gw = GNW + wv*256 + l*4;
  float vv[4] = {v0,v1,v2,v3};
  #pragma unroll
  for (int j=0;j<4;j++) X2[base+j] = X[base+j] + (vv[j]-mu)*rs*gw[j];
}

// ---------------- GEMM bt-form: C[M,N] = A[M,K] * B[N,K]^T (fp16, fp32 acc) -------
// MODE 0: gx epilogue -> [t][n][k][q][g][2b] fp16 + bias
// MODE 1: dual-B (Wg,Wu), S = silu(G)*U fp16
// MODE 2: out = X2 + acc (fp32; OF and X2 alias element-for-element, no restrict)
template<int MODE>
__global__ __launch_bounds__(256,2) void gemm_bt(
    const unsigned short* __restrict__ A, int lda,
    const unsigned short* __restrict__ B1, const unsigned short* __restrict__ B2, int ldb,
    int K, unsigned short* __restrict__ OB, float* OF,
    const float* X2, const float* __restrict__ BIAS){
  __shared__ __align__(16) char smA[128*64];
  __shared__ __align__(16) char smB[64*64];
  __shared__ __align__(16) char smB2[64*64];
  int tid = threadIdx.x, w = tid>>6, l = tid&63;
  int n0 = blockIdx.x*64, m0 = blockIdx.y*128, head = blockIdx.z;
  if constexpr (MODE==0){ A += (size_t)head*256; B1 += (size_t)head*1024*256; }
  f32x4 acc[4][2], acc2[4][2];
  f32x4 z = {0.f,0.f,0.f,0.f};
  #pragma unroll
  for (int mi=0;mi<4;mi++)
    #pragma unroll
    for (int ni=0;ni<2;ni++){ acc[mi][ni]=z; acc2[mi][ni]=z; }
  int wr = w>>1, wc = w&1;
  for (int kt = 0; kt < K; kt += 32){
    #pragma unroll
    for (int c2=0;c2<2;c2++){
      int p = w*128 + c2*64 + l;
      int rr = p>>2, u = (p&3) ^ ((rr>>1)&3);
      GLOAD16(A + (size_t)(m0+rr)*lda + kt + u*8, smA + (w*128 + c2*64)*16);
    }
    {
      int p = w*64 + l;
      int rr = p>>2, u = (p&3) ^ ((rr>>1)&3);
      GLOAD16(B1 + (size_t)(n0+rr)*ldb + kt + u*8, smB + (w*64)*16);
      if constexpr (MODE==1)
        GLOAD16(B2 + (size_t)(n0+rr)*ldb + kt + u*8, smB2 + (w*64)*16);
    }
    __syncthreads();
    short8 af[4], bf[2], bg[2];
    #pragma unroll
    for (int mi=0;mi<4;mi++) af[mi] = *(const short8*)(smA + swz(wr*64 + mi*16 + (l&15), l>>4));
    #pragma unroll
    for (int ni=0;ni<2;ni++){
      bf[ni] = *(const short8*)(smB + swz(wc*32 + ni*16 + (l&15), l>>4));
      if constexpr (MODE==1)
        bg[ni] = *(const short8*)(smB2 + swz(wc*32 + ni*16 + (l&15), l>>4));
    }
    #pragma unroll
    for (int mi=0;mi<4;mi++)
      #pragma unroll
      for (int ni=0;ni<2;ni++){
        acc[mi][ni] = __builtin_amdgcn_mfma_f32_16x16x32_f16(as_f16x8(af[mi]), as_f16x8(bf[ni]), acc[mi][ni], 0,0,0);
        if constexpr (MODE==1)
          acc2[mi][ni] = __builtin_amdgcn_mfma_f32_16x16x32_f16(as_f16x8(af[mi]), as_f16x8(bg[ni]), acc2[mi][ni], 0,0,0);
      }
    __syncthreads();
  }
  int rbase = m0 + wr*64, cbase = n0 + wc*32;
  #pragma unroll
  for (int mi=0;mi<4;mi++)
    #pragma unroll
    for (int ni=0;ni<2;ni++)
      #pragma unroll
      for (int j=0;j<4;j++){
        int gr = rbase + mi*16 + (l>>4)*4 + j;
        int gc = cbase + ni*16 + (l&15);
        float v = acc[mi][ni][j];
        if constexpr (MODE==0){
          int t = gr & 2047, b = gr >> 11;
          int g = gc >> 8, k = gc & 255;
          OB[ ((((size_t)t*4 + head)*256 + k)*4 + (b>>1))*8 + g*2 + (b&1) ]
            = f2h(v + BIAS[head*1024 + gc]);
        } else if constexpr (MODE==1){
          float u = acc2[mi][ni][j];
          float sg = v*frcp(1.f + fexp2(-v*1.44269504f));
          OB[ (size_t)gr*2752 + gc ] = f2h(sg*u);
        } else {
          size_t idx = (size_t)gr*1024 + gc;
          OF[idx] = X2[idx] + v;
        }
      }
}

// ---------------- sLSTM scan: 16 waves/WG, 16 cols/wave, 2 states/lane -----------
// A-row packing: row = 2*batch + (0=hi,1=lo). C quadrant q rows 4q..4q+3 give each
// lane hi+lo for batches 2q,2q+1 at its column -> no shuffles, all lanes busy.
// In-loop sync is lgkmcnt(0)+s_barrier ONLY (no vmcnt drain): HS stores stream,
// gx prefetch (issued at step top) is waited at its use one step later.
__global__ __launch_bounds__(1024) void scan_k(
    const unsigned short* __restrict__ GX,   // [T][4][256 k][4 q][4 g][2 db] fp16
    const signed char* __restrict__ RQ,      // frag-linear int8
    const float* __restrict__ SC,            // [4][g*256+k]
    unsigned short* __restrict__ HS){        // [T][4][8][256] fp16
  int n = blockIdx.x;
  int tid = threadIdx.x, w = tid>>6, l = tid&63;
  __shared__ __align__(16) signed char hl[2][16*272];
  for (int i = tid; i < 2*16*272; i += 1024) ((signed char*)hl)[i] = 0;

  int l15 = l & 15, q = l >> 4;

  // B-frags: wave w covers 16 cols x 4 gates x 4 K-frags.
  i32x4 wf[4][4];
  {
    const i32x4* rp = (const i32x4*)RQ + (size_t)(n*8 + (w>>1))*32*64;
    #pragma unroll
    for (int g=0; g<4; g++){
      int f = ((w&1)<<2) | g;
      #pragma unroll
      for (int kf=0; kf<4; kf++)
        wf[g][kf] = rp[(f*4+kf)*64 + l];
    }
  }

  float sch[4], scl[4];
  #pragma unroll
  for (int g=0; g<4; g++){
    float s = SC[n*1024 + g*256 + w*16 + l15];
    sch[g] = s; scl[g] = s*(1.f/127.f);
  }

  float cs[2], ns_[2], ms[2];   // per db; m kept in log2 domain
  #pragma unroll
  for (int db=0;db<2;db++){ cs[db]=0.f; ns_[db]=0.f; ms[db]=0.f; }

  const unsigned short* gp = GX + ((size_t)n*256 + w*16 + l15)*32 + q*8;
  u16x8 gxr = *(const u16x8*)gp;          // t=0
  const unsigned short* gpp = gp + 32768; // prefetch ptr (t=1)

  unsigned short* hsp = HS + ((size_t)n*8 + 2*q)*256 + w*16 + l15;
  int hlw = w*16 + l15;                   // hl col base
  int hrow = 4*q;                          // hl row base (batches 2q,2q+1)
  const float L2E = 1.44269504f;
  __syncthreads();

  int p = 0;
  for (int t = 0; t < 2048; ++t){
    i32x4 af[4];
    #pragma unroll
    for (int kf=0;kf<4;kf++)
      af[kf] = *(const i32x4*)(&hl[p][l15*272 + kf*64 + q*16]);
    u16x8 gx_nxt = *(const u16x8*)gpp;   // issue early; consumed next step
    i32x4 acc[4];
    #pragma unroll
    for (int g=0; g<4; g++){
      i32x4 a = {0,0,0,0};
      #pragma unroll
      for (int kf=0; kf<4; kf++)
        a = __builtin_amdgcn_mfma_i32_16x16x64_i8(af[kf], wf[g][kf], a, 0,0,0);
      acc[g] = a;
    }
    #pragma unroll
    for (int db=0; db<2; db++){
      float rec0 = sch[0]*(float)acc[0][2*db] + scl[0]*(float)acc[0][2*db+1];
      float rec1 = sch[1]*(float)acc[1][2*db] + scl[1]*(float)acc[1][2*db+1];
      float rec2 = sch[2]*(float)acc[2][2*db] + scl[2]*(float)acc[2][2*db+1];
      float rec3 = sch[3]*(float)acc[3][2*db] + scl[3]*(float)acc[3][2*db+1];
      float ip = h2f(gxr[0+db]) + rec0;
      float fp = h2f(gxr[2+db]) + rec1;
      float zp = h2f(gxr[4+db]) + rec2;
      float op = h2f(gxr[6+db]) + rec3;
      float ip2 = ip*L2E;
      float fp2 = fp*L2E + ms[db];
      float mn = fmaxf(fp2, ip2);
      float ig = fexp2(ip2 - mn);
      float fg = fexp2(fp2 - mn);
      float e2 = fexp2(zp*(2.f*L2E));
      float tz = 1.f - 2.f*frcp(e2 + 1.f);
      float og = frcp(1.f + fexp2(-op*L2E));
      float c  = fg*cs[db] + ig*tz;
      float nn = fg*ns_[db] + ig;
      float h  = og*c*frcp(nn);
      cs[db]=c; ns_[db]=nn; ms[db]=mn;
      float h127 = h*127.f;               // |h|<1 provably -> no clamp
      float hiq = rintf(h127);
      float loq = rintf((h127 - hiq)*127.f);
      hl[p^1][(hrow + 2*db + 0)*272 + hlw] = (signed char)(int)hiq;
      hl[p^1][(hrow + 2*db + 1)*272 + hlw] = (signed char)(int)loq;
      hsp[db*256] = f2h(h);
    }
    hsp += 8192;
    gpp += (t+2 < 2048) ? 32768 : 0;      // clamp: last iter re-reads t=2047
    gxr = gx_nxt;
    // LDS-only barrier: own ds ops drained, then workgroup sync. No vmcnt drain.
    asm volatile("s_waitcnt lgkmcnt(0)" ::: "memory");
    __builtin_amdgcn_s_barrier();
    __builtin_amdgcn_sched_barrier(0);
    p ^= 1;
  }
}

// ---------------- launch ----------------------------------------------------------
extern "C" void kernel_launch(void* const* d_in, const int* in_sizes, int n_in,
                              void* d_out, int out_size, void* d_ws, size_t ws_size,
                              hipStream_t stream){
  (void)in_sizes; (void)n_in; (void)out_size;
  const float* x    = (const float*)d_in[0];
  const float* ln1w = (const float*)d_in[1];
  const float* Wg_  = (const float*)d_in[2];
  const float* Rg_  = (const float*)d_in[3];
  const float* bg_  = (const float*)d_in[4];
  const float* gnw  = (const float*)d_in[5];
  const float* ln2w = (const float*)d_in[6];
  const float* Wgf  = (const float*)d_in[7];
  const float* Wuf  = (const float*)d_in[8];
  const float* Wdf  = (const float*)d_in[9];
  float* out = (float*)d_out;
  char* ws = (char*)d_ws;

  // lifetime-aliased workspace layout (total 187,858,944 B)
  if (ws_size < 187858944ull) return;
  unsigned short* wbt = (unsigned short*)(ws + 0);
  float*          bias= (float*)        (ws + 2097152);
  signed char*    rq  = (signed char*)  (ws + 2113536);
  float*          sc2 = (float*)        (ws + 3162112);
  unsigned short* wgt = (unsigned short*)(ws + 3178496);
  unsigned short* wut = (unsigned short*)(ws + 8814592);
  unsigned short* wdt = (unsigned short*)(ws + 14450688);
  unsigned short* xn  = (unsigned short*)(ws + 20086784);
  unsigned short* hs  = (unsigned short*)(ws + 20086784);   // aliases xn
  unsigned short* gx  = (unsigned short*)(ws + 53641216);
  unsigned short* y2  = (unsigned short*)(ws + 53641216);   // aliases gx (dead)
  unsigned short* S   = (unsigned short*)(ws + 87195648);   // aliases gx tail
  float*          x2  = out;                                 // residual stream in d_out

  prep_wbt<<<4096,256,0,stream>>>(Wg_, bg_, wbt, bias);
  prep_rq <<<4096,256,0,stream>>>(Rg_, rq, sc2);
  transpose_cast<<<dim3(86,32),256,0,stream>>>(Wgf, wgt, 1024, 2752);
  transpose_cast<<<dim3(86,32),256,0,stream>>>(Wuf, wut, 1024, 2752);
  transpose_cast<<<dim3(32,86),256,0,stream>>>(Wdf, wdt, 2752, 1024);

  rmsnorm_k<<<16384,256,0,stream>>>(x, ln1w, xn);
  gemm_bt<0><<<dim3(16,128,4),256,0,stream>>>(xn, 1024, wbt, nullptr, 256, 256,
                                              gx, nullptr, nullptr, bias);
  scan_k<<<4,1024,0,stream>>>(gx, rq, sc2, hs);
  ln_res_k<<<16384,256,0,stream>>>(hs, x, gnw, x2);
  rmsnorm_k<<<16384,256,0,stream>>>(x2, ln2w, y2);
  gemm_bt<1><<<dim3(43,128),256,0,stream>>>(y2, 1024, wgt, wut, 1024, 1024,
                                            S, nullptr, nullptr, nullptr);
  gemm_bt<2><<<dim3(16,128),256,0,stream>>>(S, 2752, wdt, nullptr, 2752, 2752,
                                            nullptr, out, x2, nullptr);
}

// Round 9
// 3574.456 us; speedup vs baseline: 2.7442x; 1.0729x over previous
//
#include <hip/hip_runtime.h>
#include <hip/hip_bf16.h>

#define DEV __device__ __forceinline__

typedef __attribute__((ext_vector_type(4))) float f32x4;
typedef __attribute__((ext_vector_type(8))) short short8;
typedef __attribute__((ext_vector_type(8))) _Float16 f16x8;
typedef __attribute__((ext_vector_type(4))) int i32x4;
typedef __attribute__((ext_vector_type(4))) unsigned short u16x4;
typedef __attribute__((ext_vector_type(8))) unsigned short u16x8;

typedef __attribute__((address_space(3))) void lds_void;
typedef const __attribute__((address_space(1))) void g_void;
#define GLOAD16(g, l) __builtin_amdgcn_global_load_lds((g_void*)(g), (lds_void*)(l), 16, 0, 0)

DEV unsigned short f2h(float f){ union{_Float16 h; unsigned short u;} c; c.h = (_Float16)f; return c.u; }
DEV float h2f(unsigned short u){ union{unsigned short u; _Float16 h;} c; c.u = u; return (float)c.h; }
DEV f16x8 as_f16x8(short8 s){ union{short8 s; f16x8 h;} c; c.s = s; return c.h; }
DEV float fexp2(float x){
#if __has_builtin(__builtin_amdgcn_exp2f)
  return __builtin_amdgcn_exp2f(x);
#else
  return exp2f(x);
#endif
}
DEV float frcp(float x){
#if __has_builtin(__builtin_amdgcn_rcpf)
  return __builtin_amdgcn_rcpf(x);
#else
  return 1.f/x;
#endif
}
DEV float wsum(float v){
  #pragma unroll
  for(int o=32;o;o>>=1) v += __shfl_xor(v,o,64);
  return v;
}
DEV float wmax_(float v){
  #pragma unroll
  for(int o=32;o;o>>=1) v = fmaxf(v,__shfl_xor(v,o,64));
  return v;
}
// XOR swizzle for [rows][32 fp16] LDS tiles, row stride 64B, 16B units.
DEV int swz(int row, int unit){ return row*64 + ((unit ^ ((row>>1)&3))<<4); }

// ---------------- prep: W_gates fp32 -> fp16 bt-layout [n][g*256+k][h] -----------
__global__ __launch_bounds__(256) void prep_wbt(const float* __restrict__ W,
    const float* __restrict__ BG, unsigned short* __restrict__ WBT, float* __restrict__ BIAS){
  int bid = blockIdx.x;                 // (g,n,k) row-major, 4096 blocks
  int g = bid>>10, n = (bid>>8)&3, k = bid&255;
  int C = g*256 + k;                    // natural column code
  int h = threadIdx.x;
  WBT[((size_t)n*1024 + C)*256 + h] = f2h(W[(size_t)bid*256 + h]);
  if (h==0) BIAS[n*1024 + C] = BG[(g*4+n)*256 + k];
}

// ---------------- prep: R_gates fp32 -> int8 fragment layout + per-col scales ----
__global__ __launch_bounds__(256) void prep_rq(const float* __restrict__ R,
    signed char* __restrict__ RQ, float* __restrict__ SC){
  int bid = blockIdx.x;                 // (g,n,k)
  int g = bid>>10, n = (bid>>8)&3, k = bid&255;
  int h = threadIdx.x;
  float v = R[(size_t)bid*256 + h];
  float a = fabsf(v);
  float m = wmax_(a);
  __shared__ float red[4];
  int wv = threadIdx.x>>6, l = threadIdx.x&63;
  if (!l) red[wv] = m;
  __syncthreads();
  m = fmaxf(fmaxf(red[0],red[1]), fmaxf(red[2],red[3]));
  float s = fmaxf(m, 1e-20f) * (1.f/127.f);
  int q = (int)rintf(v/s);
  q = q > 127 ? 127 : (q < -127 ? -127 : q);
  int w  = k>>5, kblk = (k>>4)&1, f = (kblk<<2)|g, kf = h>>6;
  int ln = (k&15) | (((h>>4)&3)<<4);
  int j  = h&15;
  RQ[ (((size_t)(n*8+w)*32 + (f*4+kf))*64 + ln)*16 + j ] = (signed char)q;
  if (h==0) SC[n*1024 + g*256 + k] = s * (1.f/127.f);  // rec = SC*(acc_hi + acc_lo/127)
}

// ---------------- prep: transpose fp32 [K][N] -> fp16 [N][K] ----------------------
__global__ __launch_bounds__(256) void transpose_cast(const float* __restrict__ IN,
    unsigned short* __restrict__ OUT, int K, int N){
  __shared__ float tile[32][33];
  int n0 = blockIdx.x*32, k0 = blockIdx.y*32;
  int c = threadIdx.x&31, r4 = threadIdx.x>>5;
  #pragma unroll
  for (int rr = r4; rr < 32; rr += 8) tile[rr][c] = IN[(size_t)(k0+rr)*N + n0 + c];
  __syncthreads();
  #pragma unroll
  for (int rr = r4; rr < 32; rr += 8) OUT[(size_t)(n0+rr)*K + k0 + c] = f2h(tile[c][rr]);
}

// ---------------- rmsnorm fp32 -> fp16 -------------------------------------------
__global__ __launch_bounds__(256) void rmsnorm_k(const float* __restrict__ X,
    const float* __restrict__ W, unsigned short* __restrict__ O){
  size_t row = blockIdx.x;
  const f32x4* xp = (const f32x4*)(X + row*1024);
  f32x4 v = xp[threadIdx.x];
  float s = v[0]*v[0]+v[1]*v[1]+v[2]*v[2]+v[3]*v[3];
  s = wsum(s);
  __shared__ float red[4];
  int wv = threadIdx.x>>6, l = threadIdx.x&63;
  if (!l) red[wv] = s;
  __syncthreads();
  float tot = red[0]+red[1]+red[2]+red[3];
  float rs = rsqrtf(tot*(1.f/1024.f) + 1e-6f);
  int c = threadIdx.x*4;
  u16x4 o;
  #pragma unroll
  for (int j=0;j<4;j++) o[j] = f2h(v[j]*rs*W[c+j]);
  *(u16x4*)(O + row*1024 + c) = o;
}

// ---------------- multihead LN + residual: x2 = x + LN(hs)*gn_w -------------------
__global__ __launch_bounds__(256) void ln_res_k(const unsigned short* __restrict__ HS,
    const float* __restrict__ X, const float* __restrict__ GNW, float* X2){
  int bid = blockIdx.x; int b = bid>>11, t = bid&2047;
  int wv = threadIdx.x>>6, l = threadIdx.x&63;   // wave = head
  const unsigned short* hp = HS + (((size_t)t*4 + wv)*8 + b)*256 + l*4;
  u16x4 hv = *(const u16x4*)hp;
  float v0=h2f(hv[0]), v1=h2f(hv[1]), v2=h2f(hv[2]), v3=h2f(hv[3]);
  float s  = wsum(v0+v1+v2+v3);
  float s2 = wsum(v0*v0+v1*v1+v2*v2+v3*v3);
  float mu = s*(1.f/256.f);
  float var = s2*(1.f/256.f) - mu*mu;
  float rs = rsqrtf(var + 1e-5f);
  size_t base = ((size_t)b*2048 + t)*1024 + wv*256 + l*4;
  const float* gw = GNW + wv*256 + l*4;
  float vv[4] = {v0,v1,v2,v3};
  #pragma unroll
  for (int j=0;j<4;j++) X2[base+j] = X[base+j] + (vv[j]-mu)*rs*gw[j];
}

// ---------------- GEMM bt-form: C[M,N] = A[M,K] * B[N,K]^T (fp16, fp32 acc) -------
// MODE 0: gx epilogue -> [t][n][k][q][g][2b] fp16 + bias
// MODE 1: dual-B (Wg,Wu), S = silu(G)*U fp16
// MODE 2: out = X2 + acc (fp32; OF and X2 alias element-for-element, no restrict)
template<int MODE>
__global__ __launch_bounds__(256,2) void gemm_bt(
    const unsigned short* __restrict__ A, int lda,
    const unsigned short* __restrict__ B1, const unsigned short* __restrict__ B2, int ldb,
    int K, unsigned short* __restrict__ OB, float* OF,
    const float* X2, const float* __restrict__ BIAS){
  __shared__ __align__(16) char smA[128*64];
  __shared__ __align__(16) char smB[64*64];
  __shared__ __align__(16) char smB2[64*64];
  int tid = threadIdx.x, w = tid>>6, l = tid&63;
  int n0 = blockIdx.x*64, m0 = blockIdx.y*128, head = blockIdx.z;
  if constexpr (MODE==0){ A += (size_t)head*256; B1 += (size_t)head*1024*256; }
  f32x4 acc[4][2], acc2[4][2];
  f32x4 z = {0.f,0.f,0.f,0.f};
  #pragma unroll
  for (int mi=0;mi<4;mi++)
    #pragma unroll
    for (int ni=0;ni<2;ni++){ acc[mi][ni]=z; acc2[mi][ni]=z; }
  int wr = w>>1, wc = w&1;
  for (int kt = 0; kt < K; kt += 32){
    #pragma unroll
    for (int c2=0;c2<2;c2++){
      int p = w*128 + c2*64 + l;
      int rr = p>>2, u = (p&3) ^ ((rr>>1)&3);
      GLOAD16(A + (size_t)(m0+rr)*lda + kt + u*8, smA + (w*128 + c2*64)*16);
    }
    {
      int p = w*64 + l;
      int rr = p>>2, u = (p&3) ^ ((rr>>1)&3);
      GLOAD16(B1 + (size_t)(n0+rr)*ldb + kt + u*8, smB + (w*64)*16);
      if constexpr (MODE==1)
        GLOAD16(B2 + (size_t)(n0+rr)*ldb + kt + u*8, smB2 + (w*64)*16);
    }
    __syncthreads();
    short8 af[4], bf[2], bg[2];
    #pragma unroll
    for (int mi=0;mi<4;mi++) af[mi] = *(const short8*)(smA + swz(wr*64 + mi*16 + (l&15), l>>4));
    #pragma unroll
    for (int ni=0;ni<2;ni++){
      bf[ni] = *(const short8*)(smB + swz(wc*32 + ni*16 + (l&15), l>>4));
      if constexpr (MODE==1)
        bg[ni] = *(const short8*)(smB2 + swz(wc*32 + ni*16 + (l&15), l>>4));
    }
    #pragma unroll
    for (int mi=0;mi<4;mi++)
      #pragma unroll
      for (int ni=0;ni<2;ni++){
        acc[mi][ni] = __builtin_amdgcn_mfma_f32_16x16x32_f16(as_f16x8(af[mi]), as_f16x8(bf[ni]), acc[mi][ni], 0,0,0);
        if constexpr (MODE==1)
          acc2[mi][ni] = __builtin_amdgcn_mfma_f32_16x16x32_f16(as_f16x8(af[mi]), as_f16x8(bg[ni]), acc2[mi][ni], 0,0,0);
      }
    __syncthreads();
  }
  int rbase = m0 + wr*64, cbase = n0 + wc*32;
  #pragma unroll
  for (int mi=0;mi<4;mi++)
    #pragma unroll
    for (int ni=0;ni<2;ni++)
      #pragma unroll
      for (int j=0;j<4;j++){
        int gr = rbase + mi*16 + (l>>4)*4 + j;
        int gc = cbase + ni*16 + (l&15);
        float v = acc[mi][ni][j];
        if constexpr (MODE==0){
          int t = gr & 2047, b = gr >> 11;
          int g = gc >> 8, k = gc & 255;
          OB[ ((((size_t)t*4 + head)*256 + k)*4 + (b>>1))*8 + g*2 + (b&1) ]
            = f2h(v + BIAS[head*1024 + gc]);
        } else if constexpr (MODE==1){
          float u = acc2[mi][ni][j];
          float sg = v*frcp(1.f + fexp2(-v*1.44269504f));
          OB[ (size_t)gr*2752 + gc ] = f2h(sg*u);
        } else {
          size_t idx = (size_t)gr*1024 + gc;
          OF[idx] = X2[idx] + v;
        }
      }
}

// ---------------- sLSTM scan: 8 WGs = (head, 4-batch group), 1 state/lane --------
// A-row packing: row = 4*b_local + (0=hi,1=lo); rows 4b+2,3 stay zero. C quadrant
// q row 4q+j gives lane its single state (k = w*16+l15, b_local = q): j=0 hi, j=1 lo.
// MFMA sweep per WG unchanged (256/step); epilogue VALU halves vs round 8.
// In-loop sync: lgkmcnt(0)+s_barrier only (no vmcnt drain); gx prefetch 1 step ahead.
__global__ __launch_bounds__(1024) void scan_k(
    const unsigned short* __restrict__ GX,   // [T][4][256 k][4 q4][4 g][2 db] fp16
    const signed char* __restrict__ RQ,      // frag-linear int8
    const float* __restrict__ SC,            // [4][g*256+k]
    unsigned short* __restrict__ HS){        // [T][4][8][256] fp16
  int bid = blockIdx.x;
  int n = bid >> 1, bg = bid & 1;           // head, batch-group (batches bg*4..bg*4+3)
  int tid = threadIdx.x, w = tid>>6, l = tid&63;
  __shared__ __align__(16) signed char hl[2][16*272];
  for (int i = tid; i < 2*16*272; i += 1024) ((signed char*)hl)[i] = 0;

  int l15 = l & 15, q = l >> 4;             // q = local batch index

  // B-frags: wave w covers 16 cols x 4 gates x 4 K-frags (same as before).
  i32x4 wf[4][4];
  {
    const i32x4* rp = (const i32x4*)RQ + (size_t)(n*8 + (w>>1))*32*64;
    #pragma unroll
    for (int g=0; g<4; g++){
      int f = ((w&1)<<2) | g;
      #pragma unroll
      for (int kf=0; kf<4; kf++)
        wf[g][kf] = rp[(f*4+kf)*64 + l];
    }
  }

  float sch[4], scl[4];
  #pragma unroll
  for (int g=0; g<4; g++){
    float s = SC[n*1024 + g*256 + w*16 + l15];
    sch[g] = s; scl[g] = s*(1.f/127.f);
  }

  float cs = 0.f, ns_ = 0.f, ms = 0.f;      // single state; m in log2 domain
  int db = q & 1;                            // gx sub-index for this lane's batch

  const unsigned short* gp = GX + ((size_t)n*256 + w*16 + l15)*32 + (bg*2 + (q>>1))*8;
  u16x8 gxr = *(const u16x8*)gp;            // t=0
  const unsigned short* gpp = gp + 32768;   // prefetch ptr (t=1)

  unsigned short* hsp = HS + ((size_t)n*8 + bg*4 + q)*256 + w*16 + l15;
  int hlw = w*16 + l15;                      // hl col (k index)
  int r_hi = (4*q + 0)*272 + hlw;            // hl row 4q   (hi)
  int r_lo = (4*q + 1)*272 + hlw;            // hl row 4q+1 (lo)
  const float L2E = 1.44269504f;
  __syncthreads();

  int p = 0;
  for (int t = 0; t < 2048; ++t){
    i32x4 af[4];
    #pragma unroll
    for (int kf=0;kf<4;kf++)
      af[kf] = *(const i32x4*)(&hl[p][l15*272 + kf*64 + q*16]);
    u16x8 gx_nxt = *(const u16x8*)gpp;      // issue early; consumed next step
    i32x4 acc[4];
    #pragma unroll
    for (int g=0; g<4; g++){
      i32x4 a = {0,0,0,0};
      #pragma unroll
      for (int kf=0; kf<4; kf++)
        a = __builtin_amdgcn_mfma_i32_16x16x64_i8(af[kf], wf[g][kf], a, 0,0,0);
      acc[g] = a;
    }
    {
      // single state: j=0 -> hi row, j=1 -> lo row of this lane's quadrant
      float rec0 = sch[0]*(float)acc[0][0] + scl[0]*(float)acc[0][1];
      float rec1 = sch[1]*(float)acc[1][0] + scl[1]*(float)acc[1][1];
      float rec2 = sch[2]*(float)acc[2][0] + scl[2]*(float)acc[2][1];
      float rec3 = sch[3]*(float)acc[3][0] + scl[3]*(float)acc[3][1];
      float ip = h2f(gxr[0+db]) + rec0;
      float fp = h2f(gxr[2+db]) + rec1;
      float zp = h2f(gxr[4+db]) + rec2;
      float op = h2f(gxr[6+db]) + rec3;
      float ip2 = ip*L2E;
      float fp2 = fp*L2E + ms;
      float mn = fmaxf(fp2, ip2);
      float ig = fexp2(ip2 - mn);
      float fg = fexp2(fp2 - mn);
      float e2 = fexp2(zp*(2.f*L2E));
      float tz = 1.f - 2.f*frcp(e2 + 1.f);
      float og = frcp(1.f + fexp2(-op*L2E));
      float c  = fg*cs + ig*tz;
      float nn = fg*ns_ + ig;
      float h  = og*c*frcp(nn);
      cs=c; ns_=nn; ms=mn;
      float h127 = h*127.f;                 // |h|<1 provably -> no clamp
      float hiq = rintf(h127);
      float loq = rintf((h127 - hiq)*127.f);
      hl[p^1][r_hi] = (signed char)(int)hiq;
      hl[p^1][r_lo] = (signed char)(int)loq;
      hsp[0] = f2h(h);
    }
    hsp += 8192;
    gpp += (t+2 < 2048) ? 32768 : 0;        // clamp: last iter re-reads t=2047
    gxr = gx_nxt;
    // LDS-only barrier: own ds ops drained, then workgroup sync. No vmcnt drain.
    asm volatile("s_waitcnt lgkmcnt(0)" ::: "memory");
    __builtin_amdgcn_s_barrier();
    __builtin_amdgcn_sched_barrier(0);
    p ^= 1;
  }
}

// ---------------- launch ----------------------------------------------------------
extern "C" void kernel_launch(void* const* d_in, const int* in_sizes, int n_in,
                              void* d_out, int out_size, void* d_ws, size_t ws_size,
                              hipStream_t stream){
  (void)in_sizes; (void)n_in; (void)out_size;
  const float* x    = (const float*)d_in[0];
  const float* ln1w = (const float*)d_in[1];
  const float* Wg_  = (const float*)d_in[2];
  const float* Rg_  = (const float*)d_in[3];
  const float* bg_  = (const float*)d_in[4];
  const float* gnw  = (const float*)d_in[5];
  const float* ln2w = (const float*)d_in[6];
  const float* Wgf  = (const float*)d_in[7];
  const float* Wuf  = (const float*)d_in[8];
  const float* Wdf  = (const float*)d_in[9];
  float* out = (float*)d_out;
  char* ws = (char*)d_ws;

  // lifetime-aliased workspace layout (total 187,858,944 B)
  if (ws_size < 187858944ull) return;
  unsigned short* wbt = (unsigned short*)(ws + 0);
  float*          bias= (float*)        (ws + 2097152);
  signed char*    rq  = (signed char*)  (ws + 2113536);
  float*          sc2 = (float*)        (ws + 3162112);
  unsigned short* wgt = (unsigned short*)(ws + 3178496);
  unsigned short* wut = (unsigned short*)(ws + 8814592);
  unsigned short* wdt = (unsigned short*)(ws + 14450688);
  unsigned short* xn  = (unsigned short*)(ws + 20086784);
  unsigned short* hs  = (unsigned short*)(ws + 20086784);   // aliases xn
  unsigned short* gx  = (unsigned short*)(ws + 53641216);
  unsigned short* y2  = (unsigned short*)(ws + 53641216);   // aliases gx (dead)
  unsigned short* S   = (unsigned short*)(ws + 87195648);   // aliases gx tail
  float*          x2  = out;                                 // residual stream in d_out

  prep_wbt<<<4096,256,0,stream>>>(Wg_, bg_, wbt, bias);
  prep_rq <<<4096,256,0,stream>>>(Rg_, rq, sc2);
  transpose_cast<<<dim3(86,32),256,0,stream>>>(Wgf, wgt, 1024, 2752);
  transpose_cast<<<dim3(86,32),256,0,stream>>>(Wuf, wut, 1024, 2752);
  transpose_cast<<<dim3(32,86),256,0,stream>>>(Wdf, wdt, 2752, 1024);

  rmsnorm_k<<<16384,256,0,stream>>>(x, ln1w, xn);
  gemm_bt<0><<<dim3(16,128,4),256,0,stream>>>(xn, 1024, wbt, nullptr, 256, 256,
                                              gx, nullptr, nullptr, bias);
  scan_k<<<8,1024,0,stream>>>(gx, rq, sc2, hs);
  ln_res_k<<<16384,256,0,stream>>>(hs, x, gnw, x2);
  rmsnorm_k<<<16384,256,0,stream>>>(x2, ln2w, y2);
  gemm_bt<1><<<dim3(43,128),256,0,stream>>>(y2, 1024, wgt, wut, 1024, 1024,
                                            S, nullptr, nullptr, nullptr);
  gemm_bt<2><<<dim3(16,128),256,0,stream>>>(S, 2752, wdt, nullptr, 2752, 2752,
                                            nullptr, out, x2, nullptr);
}

// Round 10
// 2790.941 us; speedup vs baseline: 3.5146x; 1.2807x over previous
//
#include <hip/hip_runtime.h>
#include <hip/hip_bf16.h>

#define DEV __device__ __forceinline__

typedef __attribute__((ext_vector_type(4))) float f32x4;
typedef __attribute__((ext_vector_type(8))) short short8;
typedef __attribute__((ext_vector_type(8))) _Float16 f16x8;
typedef __attribute__((ext_vector_type(4))) int i32x4;
typedef __attribute__((ext_vector_type(4))) unsigned short u16x4;

typedef __attribute__((address_space(3))) void lds_void;
typedef const __attribute__((address_space(1))) void g_void;
#define GLOAD16(g, l) __builtin_amdgcn_global_load_lds((g_void*)(g), (lds_void*)(l), 16, 0, 0)

DEV unsigned short f2h(float f){ union{_Float16 h; unsigned short u;} c; c.h = (_Float16)f; return c.u; }
DEV float h2f(unsigned short u){ union{unsigned short u; _Float16 h;} c; c.u = u; return (float)c.h; }
DEV f16x8 as_f16x8(short8 s){ union{short8 s; f16x8 h;} c; c.s = s; return c.h; }
DEV float fexp2(float x){
#if __has_builtin(__builtin_amdgcn_exp2f)
  return __builtin_amdgcn_exp2f(x);
#else
  return exp2f(x);
#endif
}
DEV float frcp(float x){
#if __has_builtin(__builtin_amdgcn_rcpf)
  return __builtin_amdgcn_rcpf(x);
#else
  return 1.f/x;
#endif
}
DEV float wsum(float v){
  #pragma unroll
  for(int o=32;o;o>>=1) v += __shfl_xor(v,o,64);
  return v;
}
DEV float wmax_(float v){
  #pragma unroll
  for(int o=32;o;o>>=1) v = fmaxf(v,__shfl_xor(v,o,64));
  return v;
}
// XOR swizzle for [rows][32 fp16] LDS tiles, row stride 64B, 16B units.
DEV int swz(int row, int unit){ return row*64 + ((unit ^ ((row>>1)&3))<<4); }

// ---------------- prep: W_gates fp32 -> fp16 bt-layout [n][g*256+k][h] -----------
__global__ __launch_bounds__(256) void prep_wbt(const float* __restrict__ W,
    const float* __restrict__ BG, unsigned short* __restrict__ WBT, float* __restrict__ BIAS){
  int bid = blockIdx.x;                 // (g,n,k) row-major, 4096 blocks
  int g = bid>>10, n = (bid>>8)&3, k = bid&255;
  int C = g*256 + k;                    // natural column code
  int h = threadIdx.x;
  WBT[((size_t)n*1024 + C)*256 + h] = f2h(W[(size_t)bid*256 + h]);
  if (h==0) BIAS[n*1024 + C] = BG[(g*4+n)*256 + k];
}

// ---------------- prep: R_gates fp32 -> int8 fragment layout + per-col scales ----
__global__ __launch_bounds__(256) void prep_rq(const float* __restrict__ R,
    signed char* __restrict__ RQ, float* __restrict__ SC){
  int bid = blockIdx.x;                 // (g,n,k)
  int g = bid>>10, n = (bid>>8)&3, k = bid&255;
  int h = threadIdx.x;
  float v = R[(size_t)bid*256 + h];
  float a = fabsf(v);
  float m = wmax_(a);
  __shared__ float red[4];
  int wv = threadIdx.x>>6, l = threadIdx.x&63;
  if (!l) red[wv] = m;
  __syncthreads();
  m = fmaxf(fmaxf(red[0],red[1]), fmaxf(red[2],red[3]));
  float s = fmaxf(m, 1e-20f) * (1.f/127.f);
  int q = (int)rintf(v/s);
  q = q > 127 ? 127 : (q < -127 ? -127 : q);
  int w  = k>>5, kblk = (k>>4)&1, f = (kblk<<2)|g, kf = h>>6;
  int ln = (k&15) | (((h>>4)&3)<<4);
  int j  = h&15;
  RQ[ (((size_t)(n*8+w)*32 + (f*4+kf))*64 + ln)*16 + j ] = (signed char)q;
  if (h==0) SC[n*1024 + g*256 + k] = s * (1.f/127.f);  // rec = SC*(acc_hi + acc_lo/127)
}

// ---------------- prep: transpose fp32 [K][N] -> fp16 [N][K] ----------------------
__global__ __launch_bounds__(256) void transpose_cast(const float* __restrict__ IN,
    unsigned short* __restrict__ OUT, int K, int N){
  __shared__ float tile[32][33];
  int n0 = blockIdx.x*32, k0 = blockIdx.y*32;
  int c = threadIdx.x&31, r4 = threadIdx.x>>5;
  #pragma unroll
  for (int rr = r4; rr < 32; rr += 8) tile[rr][c] = IN[(size_t)(k0+rr)*N + n0 + c];
  __syncthreads();
  #pragma unroll
  for (int rr = r4; rr < 32; rr += 8) OUT[(size_t)(n0+rr)*K + k0 + c] = f2h(tile[c][rr]);
}

// ---------------- rmsnorm fp32 -> fp16 -------------------------------------------
__global__ __launch_bounds__(256) void rmsnorm_k(const float* __restrict__ X,
    const float* __restrict__ W, unsigned short* __restrict__ O){
  size_t row = blockIdx.x;
  const f32x4* xp = (const f32x4*)(X + row*1024);
  f32x4 v = xp[threadIdx.x];
  float s = v[0]*v[0]+v[1]*v[1]+v[2]*v[2]+v[3]*v[3];
  s = wsum(s);
  __shared__ float red[4];
  int wv = threadIdx.x>>6, l = threadIdx.x&63;
  if (!l) red[wv] = s;
  __syncthreads();
  float tot = red[0]+red[1]+red[2]+red[3];
  float rs = rsqrtf(tot*(1.f/1024.f) + 1e-6f);
  int c = threadIdx.x*4;
  u16x4 o;
  #pragma unroll
  for (int j=0;j<4;j++) o[j] = f2h(v[j]*rs*W[c+j]);
  *(u16x4*)(O + row*1024 + c) = o;
}

// ---------------- multihead LN + residual: x2 = x + LN(hs)*gn_w -------------------
__global__ __launch_bounds__(256) void ln_res_k(const unsigned short* __restrict__ HS,
    const float* __restrict__ X, const float* __restrict__ GNW, float* X2){
  int bid = blockIdx.x; int b = bid>>11, t = bid&2047;
  int wv = threadIdx.x>>6, l = threadIdx.x&63;   // wave = head
  const unsigned short* hp = HS + (((size_t)t*4 + wv)*8 + b)*256 + l*4;
  u16x4 hv = *(const u16x4*)hp;
  float v0=h2f(hv[0]), v1=h2f(hv[1]), v2=h2f(hv[2]), v3=h2f(hv[3]);
  float s  = wsum(v0+v1+v2+v3);
  float s2 = wsum(v0*v0+v1*v1+v2*v2+v3*v3);
  float mu = s*(1.f/256.f);
  float var = s2*(1.f/256.f) - mu*mu;
  float rs = rsqrtf(var + 1e-5f);
  size_t base = ((size_t)b*2048 + t)*1024 + wv*256 + l*4;
  const float* gw = GNW + wv*256 + l*4;
  float vv[4] = {v0,v1,v2,v3};
  #pragma unroll
  for (int j=0;j<4;j++) X2[base+j] = X[base+j] + (vv[j]-mu)*rs*gw[j];
}

// ---------------- GEMM bt-form: C[M,N] = A[M,K] * B[N,K]^T (fp16, fp32 acc) -------
// MODE 0: gx epilogue -> [t][n][k][pair][db][g] fp16, bias added, log2-pre-scaled
// MODE 1: dual-B (Wg,Wu), S = silu(G)*U fp16
// MODE 2: out = X2 + acc (fp32; OF and X2 alias element-for-element, no restrict)
template<int MODE>
__global__ __launch_bounds__(256,2) void gemm_bt(
    const unsigned short* __restrict__ A, int lda,
    const unsigned short* __restrict__ B1, const unsigned short* __restrict__ B2, int ldb,
    int K, unsigned short* __restrict__ OB, float* OF,
    const float* X2, const float* __restrict__ BIAS){
  __shared__ __align__(16) char smA[128*64];
  __shared__ __align__(16) char smB[64*64];
  __shared__ __align__(16) char smB2[64*64];
  int tid = threadIdx.x, w = tid>>6, l = tid&63;
  int n0 = blockIdx.x*64, m0 = blockIdx.y*128, head = blockIdx.z;
  if constexpr (MODE==0){ A += (size_t)head*256; B1 += (size_t)head*1024*256; }
  f32x4 acc[4][2], acc2[4][2];
  f32x4 z = {0.f,0.f,0.f,0.f};
  #pragma unroll
  for (int mi=0;mi<4;mi++)
    #pragma unroll
    for (int ni=0;ni<2;ni++){ acc[mi][ni]=z; acc2[mi][ni]=z; }
  int wr = w>>1, wc = w&1;
  for (int kt = 0; kt < K; kt += 32){
    #pragma unroll
    for (int c2=0;c2<2;c2++){
      int p = w*128 + c2*64 + l;
      int rr = p>>2, u = (p&3) ^ ((rr>>1)&3);
      GLOAD16(A + (size_t)(m0+rr)*lda + kt + u*8, smA + (w*128 + c2*64)*16);
    }
    {
      int p = w*64 + l;
      int rr = p>>2, u = (p&3) ^ ((rr>>1)&3);
      GLOAD16(B1 + (size_t)(n0+rr)*ldb + kt + u*8, smB + (w*64)*16);
      if constexpr (MODE==1)
        GLOAD16(B2 + (size_t)(n0+rr)*ldb + kt + u*8, smB2 + (w*64)*16);
    }
    __syncthreads();
    short8 af[4], bf[2], bg[2];
    #pragma unroll
    for (int mi=0;mi<4;mi++) af[mi] = *(const short8*)(smA + swz(wr*64 + mi*16 + (l&15), l>>4));
    #pragma unroll
    for (int ni=0;ni<2;ni++){
      bf[ni] = *(const short8*)(smB + swz(wc*32 + ni*16 + (l&15), l>>4));
      if constexpr (MODE==1)
        bg[ni] = *(const short8*)(smB2 + swz(wc*32 + ni*16 + (l&15), l>>4));
    }
    #pragma unroll
    for (int mi=0;mi<4;mi++)
      #pragma unroll
      for (int ni=0;ni<2;ni++){
        acc[mi][ni] = __builtin_amdgcn_mfma_f32_16x16x32_f16(as_f16x8(af[mi]), as_f16x8(bf[ni]), acc[mi][ni], 0,0,0);
        if constexpr (MODE==1)
          acc2[mi][ni] = __builtin_amdgcn_mfma_f32_16x16x32_f16(as_f16x8(af[mi]), as_f16x8(bg[ni]), acc2[mi][ni], 0,0,0);
      }
    __syncthreads();
  }
  int rbase = m0 + wr*64, cbase = n0 + wc*32;
  #pragma unroll
  for (int mi=0;mi<4;mi++)
    #pragma unroll
    for (int ni=0;ni<2;ni++)
      #pragma unroll
      for (int j=0;j<4;j++){
        int gr = rbase + mi*16 + (l>>4)*4 + j;
        int gc = cbase + ni*16 + (l&15);
        float v = acc[mi][ni][j];
        if constexpr (MODE==0){
          int t = gr & 2047, b = gr >> 11;
          int g = gc >> 8, k = gc & 255;
          float fac = (g==2) ? 2.8853900817779268f : 1.4426950408889634f;
          OB[ (((size_t)t*4 + head)*256 + k)*32 + (b>>1)*8 + (b&1)*4 + g ]
            = f2h((v + BIAS[head*1024 + gc]) * fac);
        } else if constexpr (MODE==1){
          float u = acc2[mi][ni][j];
          float sg = v*frcp(1.f + fexp2(-v*1.44269504f));
          OB[ (size_t)gr*2752 + gc ] = f2h(sg*u);
        } else {
          size_t idx = (size_t)gr*1024 + gc;
          OF[idx] = X2[idx] + v;
        }
      }
}

// ---------------- sLSTM scan: 8 WGs = (head, 4-batch group), 1 state/lane --------
// t-loop unrolled x2 over two named LDS buffers (static addresses); gx/HS use
// uniform scalar base + 32-bit lane offset (SALU addressing); gx layout gives each
// lane its 4 gate values in one 8B load (static extracts). Pre-activations arrive
// log2-pre-scaled from gemm<0>. Sync = lgkmcnt(0)+s_barrier (no vmcnt drain).
#define SCAN_STEP(HR, HW, GXV, TT) do{                                          \
    i32x4 af[4];                                                                \
    _Pragma("unroll")                                                           \
    for (int kf=0;kf<4;kf++) af[kf] = *(const i32x4*)(&HR[ra + kf*64]);         \
    i32x4 acc[4];                                                               \
    _Pragma("unroll")                                                           \
    for (int g=0; g<4; g++){                                                    \
      i32x4 a = {0,0,0,0};                                                      \
      _Pragma("unroll")                                                         \
      for (int kf=0; kf<4; kf++)                                                \
        a = __builtin_amdgcn_mfma_i32_16x16x64_i8(af[kf], wf[g][kf], a, 0,0,0); \
      acc[g] = a;                                                               \
    }                                                                           \
    float ip2 = fmaf(sch[0],(float)acc[0][0], fmaf(scl[0],(float)acc[0][1], h2f(GXV[0]))); \
    float fpv = fmaf(sch[1],(float)acc[1][0], fmaf(scl[1],(float)acc[1][1], h2f(GXV[1]))) + ms; \
    float zp2 = fmaf(sch[2],(float)acc[2][0], fmaf(scl[2],(float)acc[2][1], h2f(GXV[2]))); \
    float op2 = fmaf(sch[3],(float)acc[3][0], fmaf(scl[3],(float)acc[3][1], h2f(GXV[3]))); \
    float mn = fmaxf(fpv, ip2);                                                 \
    float ig = fexp2(ip2 - mn);                                                 \
    float fg = fexp2(fpv - mn);                                                 \
    float e2 = fexp2(zp2);                                                      \
    float tz = fmaf(-2.f, frcp(e2 + 1.f), 1.f);                                 \
    float eo = fexp2(-op2);                                                     \
    float c  = fmaf(ig, tz, fg*cs);                                             \
    float nn = fmaf(fg, ns_, ig);                                               \
    float h  = c * frcp((1.f + eo)*nn);                                         \
    cs=c; ns_=nn; ms=mn;                                                        \
    float h127 = h*127.f;                                                       \
    float hiq = rintf(h127);                                                    \
    float loq = rintf((h127 - hiq)*127.f);                                      \
    HW[r_hi] = (signed char)(int)hiq;                                           \
    HW[r_lo] = (signed char)(int)loq;                                           \
    HS[(size_t)(TT)*8192 + hoff] = f2h(h);                                      \
  }while(0)

__global__ __launch_bounds__(1024) void scan_k(
    const unsigned short* __restrict__ GX,   // [T][4 n][256 k][4 pair][2 db][4 g] fp16
    const signed char* __restrict__ RQ,      // frag-linear int8
    const float* __restrict__ SC,            // [4][g*256+k]
    unsigned short* __restrict__ HS){        // [T][4][8][256] fp16
  int bid = blockIdx.x;
  int n = bid >> 1, bg = bid & 1;           // head, batch-group
  int tid = threadIdx.x, w = tid>>6, l = tid&63;
  __shared__ __align__(16) signed char hlA[16*272];
  __shared__ __align__(16) signed char hlB[16*272];
  for (int i = tid; i < 16*272; i += 1024){ hlA[i] = 0; hlB[i] = 0; }

  int l15 = l & 15, q = l >> 4;             // q = local batch index

  i32x4 wf[4][4];
  {
    const i32x4* rp = (const i32x4*)RQ + (size_t)(n*8 + (w>>1))*32*64;
    #pragma unroll
    for (int g=0; g<4; g++){
      int f = ((w&1)<<2) | g;
      #pragma unroll
      for (int kf=0; kf<4; kf++)
        wf[g][kf] = rp[(f*4+kf)*64 + l];
    }
  }

  float sch[4], scl[4];
  {
    const float facs[4] = {1.4426950408889634f, 1.4426950408889634f,
                           2.8853900817779268f, 1.4426950408889634f};
    #pragma unroll
    for (int g=0; g<4; g++){
      float s = SC[n*1024 + g*256 + w*16 + l15] * facs[g];
      sch[g] = s; scl[g] = s*(1.f/127.f);
    }
  }

  float cs = 0.f, ns_ = 0.f, ms = 0.f;      // single state; m in log2 domain

  int goff = (n*256 + w*16 + l15)*32 + (bg*2 + (q>>1))*8 + (q&1)*4;
  int hoff = (n*8 + bg*4 + q)*256 + w*16 + l15;
  int ra   = l15*272 + q*16;                 // A-fragment ds_read base (imm kf*64)
  int r_hi = (4*q + 0)*272 + w*16 + l15;     // write row 4q   (hi)
  int r_lo = r_hi + 272;                     // write row 4q+1 (lo)

  u16x4 gxr = *(const u16x4*)(GX + goff);    // t=0
  __syncthreads();

  for (int t = 0; t < 2048; t += 2){
    u16x4 gx1 = *(const u16x4*)(GX + (size_t)(t+1)*32768 + goff);  // prefetch t+1
    SCAN_STEP(hlA, hlB, gxr, t);
    asm volatile("s_waitcnt lgkmcnt(0)" ::: "memory");
    __builtin_amdgcn_s_barrier();
    __builtin_amdgcn_sched_barrier(0);
    int tt2 = (t+2 < 2048) ? (t+2) : 2047;
    gxr = *(const u16x4*)(GX + (size_t)tt2*32768 + goff);          // prefetch t+2
    SCAN_STEP(hlB, hlA, gx1, t+1);
    asm volatile("s_waitcnt lgkmcnt(0)" ::: "memory");
    __builtin_amdgcn_s_barrier();
    __builtin_amdgcn_sched_barrier(0);
  }
}

// ---------------- launch ----------------------------------------------------------
extern "C" void kernel_launch(void* const* d_in, const int* in_sizes, int n_in,
                              void* d_out, int out_size, void* d_ws, size_t ws_size,
                              hipStream_t stream){
  (void)in_sizes; (void)n_in; (void)out_size;
  const float* x    = (const float*)d_in[0];
  const float* ln1w = (const float*)d_in[1];
  const float* Wg_  = (const float*)d_in[2];
  const float* Rg_  = (const float*)d_in[3];
  const float* bg_  = (const float*)d_in[4];
  const float* gnw  = (const float*)d_in[5];
  const float* ln2w = (const float*)d_in[6];
  const float* Wgf  = (const float*)d_in[7];
  const float* Wuf  = (const float*)d_in[8];
  const float* Wdf  = (const float*)d_in[9];
  float* out = (float*)d_out;
  char* ws = (char*)d_ws;

  // lifetime-aliased workspace layout (total 187,858,944 B)
  if (ws_size < 187858944ull) return;
  unsigned short* wbt = (unsigned short*)(ws + 0);
  float*          bias= (float*)        (ws + 2097152);
  signed char*    rq  = (signed char*)  (ws + 2113536);
  float*          sc2 = (float*)        (ws + 3162112);
  unsigned short* wgt = (unsigned short*)(ws + 3178496);
  unsigned short* wut = (unsigned short*)(ws + 8814592);
  unsigned short* wdt = (unsigned short*)(ws + 14450688);
  unsigned short* xn  = (unsigned short*)(ws + 20086784);
  unsigned short* hs  = (unsigned short*)(ws + 20086784);   // aliases xn
  unsigned short* gx  = (unsigned short*)(ws + 53641216);
  unsigned short* y2  = (unsigned short*)(ws + 53641216);   // aliases gx (dead)
  unsigned short* S   = (unsigned short*)(ws + 87195648);   // aliases gx tail
  float*          x2  = out;                                 // residual stream in d_out

  prep_wbt<<<4096,256,0,stream>>>(Wg_, bg_, wbt, bias);
  prep_rq <<<4096,256,0,stream>>>(Rg_, rq, sc2);
  transpose_cast<<<dim3(86,32),256,0,stream>>>(Wgf, wgt, 1024, 2752);
  transpose_cast<<<dim3(86,32),256,0,stream>>>(Wuf, wut, 1024, 2752);
  transpose_cast<<<dim3(32,86),256,0,stream>>>(Wdf, wdt, 2752, 1024);

  rmsnorm_k<<<16384,256,0,stream>>>(x, ln1w, xn);
  gemm_bt<0><<<dim3(16,128,4),256,0,stream>>>(xn, 1024, wbt, nullptr, 256, 256,
                                              gx, nullptr, nullptr, bias);
  scan_k<<<8,1024,0,stream>>>(gx, rq, sc2, hs);
  ln_res_k<<<16384,256,0,stream>>>(hs, x, gnw, x2);
  rmsnorm_k<<<16384,256,0,stream>>>(x2, ln2w, y2);
  gemm_bt<1><<<dim3(43,128),256,0,stream>>>(y2, 1024, wgt, wut, 1024, 1024,
                                            S, nullptr, nullptr, nullptr);
  gemm_bt<2><<<dim3(16,128),256,0,stream>>>(S, 2752, wdt, nullptr, 2752, 2752,
                                            nullptr, out, x2, nullptr);
}

// Round 11
// 2750.798 us; speedup vs baseline: 3.5659x; 1.0146x over previous
//
#include <hip/hip_runtime.h>
#include <hip/hip_bf16.h>

#define DEV __device__ __forceinline__

typedef __attribute__((ext_vector_type(4))) float f32x4;
typedef __attribute__((ext_vector_type(8))) short short8;
typedef __attribute__((ext_vector_type(8))) _Float16 f16x8;
typedef __attribute__((ext_vector_type(4))) int i32x4;
typedef __attribute__((ext_vector_type(4))) unsigned short u16x4;

typedef __attribute__((address_space(3))) void lds_void;
typedef const __attribute__((address_space(1))) void g_void;
#define GLOAD16(g, l) __builtin_amdgcn_global_load_lds((g_void*)(g), (lds_void*)(l), 16, 0, 0)

DEV unsigned short f2h(float f){ union{_Float16 h; unsigned short u;} c; c.h = (_Float16)f; return c.u; }
DEV float h2f(unsigned short u){ union{unsigned short u; _Float16 h;} c; c.u = u; return (float)c.h; }
DEV f16x8 as_f16x8(short8 s){ union{short8 s; f16x8 h;} c; c.s = s; return c.h; }
DEV float fexp2(float x){
#if __has_builtin(__builtin_amdgcn_exp2f)
  return __builtin_amdgcn_exp2f(x);
#else
  return exp2f(x);
#endif
}
DEV float frcp(float x){
#if __has_builtin(__builtin_amdgcn_rcpf)
  return __builtin_amdgcn_rcpf(x);
#else
  return 1.f/x;
#endif
}
DEV float wsum(float v){
  #pragma unroll
  for(int o=32;o;o>>=1) v += __shfl_xor(v,o,64);
  return v;
}
DEV float wmax_(float v){
  #pragma unroll
  for(int o=32;o;o>>=1) v = fmaxf(v,__shfl_xor(v,o,64));
  return v;
}
// XOR swizzle for [rows][32 fp16] LDS tiles, row stride 64B, 16B units.
DEV int swz(int row, int unit){ return row*64 + ((unit ^ ((row>>1)&3))<<4); }

// ---------------- prep: W_gates fp32 -> fp16 bt-layout [n][g*256+k][h] -----------
__global__ __launch_bounds__(256) void prep_wbt(const float* __restrict__ W,
    const float* __restrict__ BG, unsigned short* __restrict__ WBT, float* __restrict__ BIAS){
  int bid = blockIdx.x;                 // (g,n,k) row-major, 4096 blocks
  int g = bid>>10, n = (bid>>8)&3, k = bid&255;
  int C = g*256 + k;                    // natural column code
  int h = threadIdx.x;
  WBT[((size_t)n*1024 + C)*256 + h] = f2h(W[(size_t)bid*256 + h]);
  if (h==0) BIAS[n*1024 + C] = BG[(g*4+n)*256 + k];
}

// ---------------- prep: R_gates fp32 -> int8 fragment layout + per-col scales ----
__global__ __launch_bounds__(256) void prep_rq(const float* __restrict__ R,
    signed char* __restrict__ RQ, float* __restrict__ SC){
  int bid = blockIdx.x;                 // (g,n,k)
  int g = bid>>10, n = (bid>>8)&3, k = bid&255;
  int h = threadIdx.x;
  float v = R[(size_t)bid*256 + h];
  float a = fabsf(v);
  float m = wmax_(a);
  __shared__ float red[4];
  int wv = threadIdx.x>>6, l = threadIdx.x&63;
  if (!l) red[wv] = m;
  __syncthreads();
  m = fmaxf(fmaxf(red[0],red[1]), fmaxf(red[2],red[3]));
  float s = fmaxf(m, 1e-20f) * (1.f/127.f);
  int q = (int)rintf(v/s);
  q = q > 127 ? 127 : (q < -127 ? -127 : q);
  int w  = k>>5, kblk = (k>>4)&1, f = (kblk<<2)|g, kf = h>>6;
  int ln = (k&15) | (((h>>4)&3)<<4);
  int j  = h&15;
  RQ[ (((size_t)(n*8+w)*32 + (f*4+kf))*64 + ln)*16 + j ] = (signed char)q;
  if (h==0) SC[n*1024 + g*256 + k] = s * (1.f/127.f);  // rec = SC*(acc_hi + acc_lo/127)
}

// ---------------- prep: transpose fp32 [K][N] -> fp16 [N][K] ----------------------
__global__ __launch_bounds__(256) void transpose_cast(const float* __restrict__ IN,
    unsigned short* __restrict__ OUT, int K, int N){
  __shared__ float tile[32][33];
  int n0 = blockIdx.x*32, k0 = blockIdx.y*32;
  int c = threadIdx.x&31, r4 = threadIdx.x>>5;
  #pragma unroll
  for (int rr = r4; rr < 32; rr += 8) tile[rr][c] = IN[(size_t)(k0+rr)*N + n0 + c];
  __syncthreads();
  #pragma unroll
  for (int rr = r4; rr < 32; rr += 8) OUT[(size_t)(n0+rr)*K + k0 + c] = f2h(tile[c][rr]);
}

// ---------------- rmsnorm fp32 -> fp16 -------------------------------------------
__global__ __launch_bounds__(256) void rmsnorm_k(const float* __restrict__ X,
    const float* __restrict__ W, unsigned short* __restrict__ O){
  size_t row = blockIdx.x;
  const f32x4* xp = (const f32x4*)(X + row*1024);
  f32x4 v = xp[threadIdx.x];
  float s = v[0]*v[0]+v[1]*v[1]+v[2]*v[2]+v[3]*v[3];
  s = wsum(s);
  __shared__ float red[4];
  int wv = threadIdx.x>>6, l = threadIdx.x&63;
  if (!l) red[wv] = s;
  __syncthreads();
  float tot = red[0]+red[1]+red[2]+red[3];
  float rs = rsqrtf(tot*(1.f/1024.f) + 1e-6f);
  int c = threadIdx.x*4;
  u16x4 o;
  #pragma unroll
  for (int j=0;j<4;j++) o[j] = f2h(v[j]*rs*W[c+j]);
  *(u16x4*)(O + row*1024 + c) = o;
}

// ---------------- multihead LN + residual: x2 = x + LN(hs)*gn_w -------------------
__global__ __launch_bounds__(256) void ln_res_k(const unsigned short* __restrict__ HS,
    const float* __restrict__ X, const float* __restrict__ GNW, float* X2){
  int bid = blockIdx.x; int b = bid>>11, t = bid&2047;
  int wv = threadIdx.x>>6, l = threadIdx.x&63;   // wave = head
  const unsigned short* hp = HS + (((size_t)t*4 + wv)*8 + b)*256 + l*4;
  u16x4 hv = *(const u16x4*)hp;
  float v0=h2f(hv[0]), v1=h2f(hv[1]), v2=h2f(hv[2]), v3=h2f(hv[3]);
  float s  = wsum(v0+v1+v2+v3);
  float s2 = wsum(v0*v0+v1*v1+v2*v2+v3*v3);
  float mu = s*(1.f/256.f);
  float var = s2*(1.f/256.f) - mu*mu;
  float rs = rsqrtf(var + 1e-5f);
  size_t base = ((size_t)b*2048 + t)*1024 + wv*256 + l*4;
  const float* gw = GNW + wv*256 + l*4;
  float vv[4] = {v0,v1,v2,v3};
  #pragma unroll
  for (int j=0;j<4;j++) X2[base+j] = X[base+j] + (vv[j]-mu)*rs*gw[j];
}

// ---------------- GEMM bt-form, 128x128 tile (m97 structure) ----------------------
// C[M,N] = A[M,K] * B[N,K]^T (fp16, fp32 acc). 4 waves, each 64x64 (4x4 frags).
// MODE 0: gx epilogue -> [t][n][k][pair][db][g] fp16, bias added, log2-pre-scaled
// MODE 1: dual-B (Wg,Wu), S = silu(G)*U fp16, cols masked to NV
// MODE 2: out = X2 + acc (fp32; OF and X2 alias element-for-element, no restrict)
template<int MODE>
__global__ __launch_bounds__(256,2) void gemm_bt(
    const unsigned short* __restrict__ A, int lda,
    const unsigned short* __restrict__ B1, const unsigned short* __restrict__ B2, int ldb,
    int K, int NV, unsigned short* __restrict__ OB, float* OF,
    const float* X2, const float* __restrict__ BIAS){
  __shared__ __align__(16) char smA[128*64];
  __shared__ __align__(16) char smB[128*64];
  __shared__ __align__(16) char smB2[(MODE==1) ? 128*64 : 16];
  int tid = threadIdx.x, w = tid>>6, l = tid&63;
  int n0 = blockIdx.x*128, m0 = blockIdx.y*128, head = blockIdx.z;
  if constexpr (MODE==0){ A += (size_t)head*256; B1 += (size_t)head*1024*256; }
  f32x4 acc[4][4], acc2[(MODE==1)?4:1][4];
  f32x4 z = {0.f,0.f,0.f,0.f};
  #pragma unroll
  for (int mi=0;mi<4;mi++)
    #pragma unroll
    for (int ni=0;ni<4;ni++){
      acc[mi][ni]=z;
      if constexpr (MODE==1) acc2[mi][ni]=z;
    }
  int wr = w>>1, wc = w&1;
  for (int kt = 0; kt < K; kt += 32){
    #pragma unroll
    for (int c2=0;c2<2;c2++){
      int p = c2*256 + tid;
      int rr = p>>2, u = (p&3) ^ ((rr>>1)&3);
      int ldsb = (c2*256 + w*64)*16;
      GLOAD16(A  + (size_t)(m0+rr)*lda + kt + u*8, smA  + ldsb);
      GLOAD16(B1 + (size_t)(n0+rr)*ldb + kt + u*8, smB  + ldsb);
      if constexpr (MODE==1)
        GLOAD16(B2 + (size_t)(n0+rr)*ldb + kt + u*8, smB2 + ldsb);
    }
    __syncthreads();
    short8 af[4], bf[4], bg[(MODE==1)?4:1];
    #pragma unroll
    for (int mi=0;mi<4;mi++) af[mi] = *(const short8*)(smA + swz(wr*64 + mi*16 + (l&15), l>>4));
    #pragma unroll
    for (int ni=0;ni<4;ni++){
      bf[ni] = *(const short8*)(smB + swz(wc*64 + ni*16 + (l&15), l>>4));
      if constexpr (MODE==1)
        bg[ni] = *(const short8*)(smB2 + swz(wc*64 + ni*16 + (l&15), l>>4));
    }
    #pragma unroll
    for (int mi=0;mi<4;mi++)
      #pragma unroll
      for (int ni=0;ni<4;ni++){
        acc[mi][ni] = __builtin_amdgcn_mfma_f32_16x16x32_f16(as_f16x8(af[mi]), as_f16x8(bf[ni]), acc[mi][ni], 0,0,0);
        if constexpr (MODE==1)
          acc2[mi][ni] = __builtin_amdgcn_mfma_f32_16x16x32_f16(as_f16x8(af[mi]), as_f16x8(bg[ni]), acc2[mi][ni], 0,0,0);
      }
    __syncthreads();
  }
  int rbase = m0 + wr*64, cbase = n0 + wc*64;
  #pragma unroll
  for (int mi=0;mi<4;mi++)
    #pragma unroll
    for (int ni=0;ni<4;ni++)
      #pragma unroll
      for (int j=0;j<4;j++){
        int gr = rbase + mi*16 + (l>>4)*4 + j;
        int gc = cbase + ni*16 + (l&15);
        float v = acc[mi][ni][j];
        if constexpr (MODE==0){
          int t = gr & 2047, b = gr >> 11;
          int g = gc >> 8, k = gc & 255;
          float fac = (g==2) ? 2.8853900817779268f : 1.4426950408889634f;
          OB[ (((size_t)t*4 + head)*256 + k)*32 + (b>>1)*8 + (b&1)*4 + g ]
            = f2h((v + BIAS[head*1024 + gc]) * fac);
        } else if constexpr (MODE==1){
          if (gc < NV){
            float u = acc2[mi][ni][j];
            float sg = v*frcp(1.f + fexp2(-v*1.44269504f));
            OB[ (size_t)gr*2752 + gc ] = f2h(sg*u);
          }
        } else {
          size_t idx = (size_t)gr*1024 + gc;
          OF[idx] = X2[idx] + v;
        }
      }
}

// ---------------- sLSTM scan: 8 WGs = (head, 4-batch group), 1 state/lane --------
// t-loop unrolled x2 over two named LDS buffers (static addresses); gx/HS use
// uniform scalar base + 32-bit lane offset (SALU addressing); gx layout gives each
// lane its 4 gate values in one 8B load (static extracts). Pre-activations arrive
// log2-pre-scaled from gemm<0>. Sync = lgkmcnt(0)+s_barrier (no vmcnt drain).
#define SCAN_STEP(HR, HW, GXV, TT) do{                                          \
    i32x4 af[4];                                                                \
    _Pragma("unroll")                                                           \
    for (int kf=0;kf<4;kf++) af[kf] = *(const i32x4*)(&HR[ra + kf*64]);         \
    i32x4 acc[4];                                                               \
    _Pragma("unroll")                                                           \
    for (int g=0; g<4; g++){                                                    \
      i32x4 a = {0,0,0,0};                                                      \
      _Pragma("unroll")                                                         \
      for (int kf=0; kf<4; kf++)                                                \
        a = __builtin_amdgcn_mfma_i32_16x16x64_i8(af[kf], wf[g][kf], a, 0,0,0); \
      acc[g] = a;                                                               \
    }                                                                           \
    float ip2 = fmaf(sch[0],(float)acc[0][0], fmaf(scl[0],(float)acc[0][1], h2f(GXV[0]))); \
    float fpv = fmaf(sch[1],(float)acc[1][0], fmaf(scl[1],(float)acc[1][1], h2f(GXV[1]))) + ms; \
    float zp2 = fmaf(sch[2],(float)acc[2][0], fmaf(scl[2],(float)acc[2][1], h2f(GXV[2]))); \
    float op2 = fmaf(sch[3],(float)acc[3][0], fmaf(scl[3],(float)acc[3][1], h2f(GXV[3]))); \
    float mn = fmaxf(fpv, ip2);                                                 \
    float ig = fexp2(ip2 - mn);                                                 \
    float fg = fexp2(fpv - mn);                                                 \
    float e2 = fexp2(zp2);                                                      \
    float tz = fmaf(-2.f, frcp(e2 + 1.f), 1.f);                                 \
    float eo = fexp2(-op2);                                                     \
    float c  = fmaf(ig, tz, fg*cs);                                             \
    float nn = fmaf(fg, ns_, ig);                                               \
    float h  = c * frcp((1.f + eo)*nn);                                         \
    cs=c; ns_=nn; ms=mn;                                                        \
    float h127 = h*127.f;                                                       \
    float hiq = rintf(h127);                                                    \
    float loq = rintf((h127 - hiq)*127.f);                                      \
    HW[r_hi] = (signed char)(int)hiq;                                           \
    HW[r_lo] = (signed char)(int)loq;                                           \
    HS[(size_t)(TT)*8192 + hoff] = f2h(h);                                      \
  }while(0)

__global__ __launch_bounds__(1024) void scan_k(
    const unsigned short* __restrict__ GX,   // [T][4 n][256 k][4 pair][2 db][4 g] fp16
    const signed char* __restrict__ RQ,      // frag-linear int8
    const float* __restrict__ SC,            // [4][g*256+k]
    unsigned short* __restrict__ HS){        // [T][4][8][256] fp16
  int bid = blockIdx.x;
  int n = bid >> 1, bg = bid & 1;           // head, batch-group
  int tid = threadIdx.x, w = tid>>6, l = tid&63;
  __shared__ __align__(16) signed char hlA[16*272];
  __shared__ __align__(16) signed char hlB[16*272];
  for (int i = tid; i < 16*272; i += 1024){ hlA[i] = 0; hlB[i] = 0; }

  int l15 = l & 15, q = l >> 4;             // q = local batch index

  i32x4 wf[4][4];
  {
    const i32x4* rp = (const i32x4*)RQ + (size_t)(n*8 + (w>>1))*32*64;
    #pragma unroll
    for (int g=0; g<4; g++){
      int f = ((w&1)<<2) | g;
      #pragma unroll
      for (int kf=0; kf<4; kf++)
        wf[g][kf] = rp[(f*4+kf)*64 + l];
    }
  }

  float sch[4], scl[4];
  {
    const float facs[4] = {1.4426950408889634f, 1.4426950408889634f,
                           2.8853900817779268f, 1.4426950408889634f};
    #pragma unroll
    for (int g=0; g<4; g++){
      float s = SC[n*1024 + g*256 + w*16 + l15] * facs[g];
      sch[g] = s; scl[g] = s*(1.f/127.f);
    }
  }

  float cs = 0.f, ns_ = 0.f, ms = 0.f;      // single state; m in log2 domain

  int goff = (n*256 + w*16 + l15)*32 + (bg*2 + (q>>1))*8 + (q&1)*4;
  int hoff = (n*8 + bg*4 + q)*256 + w*16 + l15;
  int ra   = l15*272 + q*16;                 // A-fragment ds_read base (imm kf*64)
  int r_hi = (4*q + 0)*272 + w*16 + l15;     // write row 4q   (hi)
  int r_lo = r_hi + 272;                     // write row 4q+1 (lo)

  u16x4 gxr = *(const u16x4*)(GX + goff);    // t=0
  __syncthreads();

  for (int t = 0; t < 2048; t += 2){
    u16x4 gx1 = *(const u16x4*)(GX + (size_t)(t+1)*32768 + goff);  // prefetch t+1
    SCAN_STEP(hlA, hlB, gxr, t);
    asm volatile("s_waitcnt lgkmcnt(0)" ::: "memory");
    __builtin_amdgcn_s_barrier();
    __builtin_amdgcn_sched_barrier(0);
    int tt2 = (t+2 < 2048) ? (t+2) : 2047;
    gxr = *(const u16x4*)(GX + (size_t)tt2*32768 + goff);          // prefetch t+2
    SCAN_STEP(hlB, hlA, gx1, t+1);
    asm volatile("s_waitcnt lgkmcnt(0)" ::: "memory");
    __builtin_amdgcn_s_barrier();
    __builtin_amdgcn_sched_barrier(0);
  }
}

// ---------------- launch ----------------------------------------------------------
extern "C" void kernel_launch(void* const* d_in, const int* in_sizes, int n_in,
                              void* d_out, int out_size, void* d_ws, size_t ws_size,
                              hipStream_t stream){
  (void)in_sizes; (void)n_in; (void)out_size;
  const float* x    = (const float*)d_in[0];
  const float* ln1w = (const float*)d_in[1];
  const float* Wg_  = (const float*)d_in[2];
  const float* Rg_  = (const float*)d_in[3];
  const float* bg_  = (const float*)d_in[4];
  const float* gnw  = (const float*)d_in[5];
  const float* ln2w = (const float*)d_in[6];
  const float* Wgf  = (const float*)d_in[7];
  const float* Wuf  = (const float*)d_in[8];
  const float* Wdf  = (const float*)d_in[9];
  float* out = (float*)d_out;
  char* ws = (char*)d_ws;

  // lifetime-aliased workspace layout (total 187,858,944 B)
  if (ws_size < 187858944ull) return;
  unsigned short* wbt = (unsigned short*)(ws + 0);
  float*          bias= (float*)        (ws + 2097152);
  signed char*    rq  = (signed char*)  (ws + 2113536);
  float*          sc2 = (float*)        (ws + 3162112);
  unsigned short* wgt = (unsigned short*)(ws + 3178496);
  unsigned short* wut = (unsigned short*)(ws + 8814592);
  unsigned short* wdt = (unsigned short*)(ws + 14450688);
  unsigned short* xn  = (unsigned short*)(ws + 20086784);
  unsigned short* hs  = (unsigned short*)(ws + 20086784);   // aliases xn
  unsigned short* gx  = (unsigned short*)(ws + 53641216);
  unsigned short* y2  = (unsigned short*)(ws + 53641216);   // aliases gx (dead)
  unsigned short* S   = (unsigned short*)(ws + 87195648);   // aliases gx tail
  float*          x2  = out;                                 // residual stream in d_out

  prep_wbt<<<4096,256,0,stream>>>(Wg_, bg_, wbt, bias);
  prep_rq <<<4096,256,0,stream>>>(Rg_, rq, sc2);
  transpose_cast<<<dim3(86,32),256,0,stream>>>(Wgf, wgt, 1024, 2752);
  transpose_cast<<<dim3(86,32),256,0,stream>>>(Wuf, wut, 1024, 2752);
  transpose_cast<<<dim3(32,86),256,0,stream>>>(Wdf, wdt, 2752, 1024);

  rmsnorm_k<<<16384,256,0,stream>>>(x, ln1w, xn);
  gemm_bt<0><<<dim3(8,128,4),256,0,stream>>>(xn, 1024, wbt, nullptr, 256, 256, 1024,
                                             gx, nullptr, nullptr, bias);
  scan_k<<<8,1024,0,stream>>>(gx, rq, sc2, hs);
  ln_res_k<<<16384,256,0,stream>>>(hs, x, gnw, x2);
  rmsnorm_k<<<16384,256,0,stream>>>(x2, ln2w, y2);
  gemm_bt<1><<<dim3(22,128),256,0,stream>>>(y2, 1024, wgt, wut, 1024, 1024, 2752,
                                            S, nullptr, nullptr, nullptr);
  gemm_bt<2><<<dim3(8,128),256,0,stream>>>(S, 2752, wdt, nullptr, 2752, 2752, 1024,
                                           nullptr, out, x2, nullptr);
}